// Round 1
// baseline (1365.390 us; speedup 1.0000x reference)
//
#include <hip/hip_runtime.h>
#include <math.h>

#define NHEAD 6
#define HP 8      // padded per-node head stride
#define NEG_SLOPE 0.2f

__device__ __forceinline__ void atomic_max_float(float* addr, float val) {
    if (val >= 0.0f) {
        atomicMax((int*)addr, __float_as_int(val));
    } else {
        atomicMin((unsigned int*)addr, __float_as_uint(val));
    }
}

// Per-node prep for one GAT layer:
//   xh = x @ W  ([N,32]@[32,192]), alpha_src/dst = sum_c xh*a, init m/denom/y.
// x row is gathered via gidx (layer 1: item indices into i_table), or identity.
__global__ __launch_bounds__(192) void k_node_prep(
    const float* __restrict__ xsrc, const int* __restrict__ gidx,
    const float* __restrict__ W, const float* __restrict__ a_src,
    const float* __restrict__ a_dst, const float* __restrict__ bias,
    float* __restrict__ xh, float* __restrict__ asrc, float* __restrict__ adst,
    float* __restrict__ m, float* __restrict__ denom, float* __restrict__ y,
    int N)
{
    __shared__ float Wl[32 * 192];
    __shared__ float xs[32];
    const int t = threadIdx.x;          // t = h*32 + c, t in [0,192)
    for (int i = t; i < 32 * 192; i += 192) Wl[i] = W[i];
    const float avs = a_src[t];
    const float avd = a_dst[t];
    const float bc  = bias[t & 31];
    const int h = t >> 5;
    const int c = t & 31;
    __syncthreads();

    for (int n = blockIdx.x; n < N; n += gridDim.x) {
        const int row = gidx ? gidx[n] : n;
        if (t < 32) xs[t] = xsrc[(size_t)row * 32 + t];
        __syncthreads();
        float acc = 0.f;
        #pragma unroll
        for (int k = 0; k < 32; ++k) acc = fmaf(xs[k], Wl[k * 192 + t], acc);
        xh[(size_t)n * 192 + t] = acc;
        float ps = acc * avs;
        float pd = acc * avd;
        // reduce across the 32 channel lanes (wave=64 covers 2 heads; xor<=16
        // stays within each 32-lane half)
        #pragma unroll
        for (int off = 16; off > 0; off >>= 1) {
            ps += __shfl_xor(ps, off);
            pd += __shfl_xor(pd, off);
        }
        if (c == 0) { asrc[n * HP + h] = ps; adst[n * HP + h] = pd; }
        if (t < HP) { m[n * HP + t] = -3.4e38f; denom[n * HP + t] = 0.f; }
        if (t < 32) y[n * 32 + t] = bc;   // y starts at bias; edges add mean
        __syncthreads();
    }
}

// Pass 1 over edges (incl. self loops): segment max of leaky_relu scores.
__global__ __launch_bounds__(256) void k_edge_max(
    const int* __restrict__ g, int E, int N,
    const float* __restrict__ asrc, const float* __restrict__ adst,
    float* __restrict__ m)
{
    int e = blockIdx.x * blockDim.x + threadIdx.x;
    int Et = E + N;
    if (e >= Et) return;
    int s, d;
    if (e < E) { s = g[e]; d = g[E + e]; } else { s = e - E; d = s; }
    #pragma unroll
    for (int hh = 0; hh < NHEAD; ++hh) {
        float v = asrc[s * HP + hh] + adst[d * HP + hh];
        v = (v >= 0.f) ? v : NEG_SLOPE * v;
        atomic_max_float(&m[d * HP + hh], v);
    }
}

// Pass 2: e_exp = exp(score - m[dst]); denom[dst] += e_exp; store e_exp.
__global__ __launch_bounds__(256) void k_edge_exp(
    const int* __restrict__ g, int E, int N,
    const float* __restrict__ asrc, const float* __restrict__ adst,
    const float* __restrict__ m,
    float* __restrict__ eexp, float* __restrict__ denom)
{
    int e = blockIdx.x * blockDim.x + threadIdx.x;
    int Et = E + N;
    if (e >= Et) return;
    int s, d;
    if (e < E) { s = g[e]; d = g[E + e]; } else { s = e - E; d = s; }
    #pragma unroll
    for (int hh = 0; hh < NHEAD; ++hh) {
        float v = asrc[s * HP + hh] + adst[d * HP + hh];
        v = (v >= 0.f) ? v : NEG_SLOPE * v;
        float ve = expf(v - m[d * HP + hh]);
        eexp[(size_t)e * NHEAD + hh] = ve;
        atomicAdd(&denom[d * HP + hh], ve);
    }
}

// denom -> 1/(denom + 1e-16)
__global__ __launch_bounds__(256) void k_inv(float* __restrict__ denom, int n)
{
    int i = blockIdx.x * blockDim.x + threadIdx.x;
    if (i < n) denom[i] = 1.f / (denom[i] + 1e-16f);
}

// Pass 3: y[dst][c] += (1/6) * sum_h alpha_h * xh[src][h][c].
// One 32-lane group per edge, lane = channel c.
__global__ __launch_bounds__(256) void k_edge_aggr(
    const int* __restrict__ g, int E, int N,
    const float* __restrict__ eexp, const float* __restrict__ invden,
    const float* __restrict__ xh, float* __restrict__ y)
{
    int gid = blockIdx.x * blockDim.x + threadIdx.x;
    int e = gid >> 5;
    int c = gid & 31;
    int Et = E + N;
    if (e >= Et) return;
    int s, d;
    if (e < E) { s = g[e]; d = g[E + e]; } else { s = e - E; d = s; }
    float acc = 0.f;
    #pragma unroll
    for (int hh = 0; hh < NHEAD; ++hh) {
        float a = eexp[(size_t)e * NHEAD + hh] * invden[d * HP + hh];
        acc = fmaf(a, xh[(size_t)s * 192 + hh * 32 + c], acc);
    }
    atomicAdd(&y[d * 32 + c], acc * (1.f / 6.f));
}

// Collapse MLP head: w_eff[i] = sum_o lw1[i][o]*lw2[o]; b_eff = lb1.lw2 + lb2.
__global__ void k_mlp_collapse(
    const float* __restrict__ lw1, const float* __restrict__ lb1,
    const float* __restrict__ lw2, const float* __restrict__ lb2,
    float* __restrict__ weff)
{
    int i = threadIdx.x;   // 64 threads
    float acc = 0.f;
    for (int o = 0; o < 64; ++o) acc += lw1[i * 64 + o] * lw2[o];
    weff[i] = acc;
    if (i == 0) {
        float b = lb2[0];
        for (int o = 0; o < 64; ++o) b += lb1[o] * lw2[o];
        weff[64] = b;
    }
}

// Final: out[n] = sigmoid( [u_emb | y2] . w_eff + b_eff )
__global__ __launch_bounds__(256) void k_final(
    const int* __restrict__ user, const float* __restrict__ u_table,
    const float* __restrict__ y2, const float* __restrict__ weff,
    float* __restrict__ out, int B)
{
    int n = blockIdx.x * blockDim.x + threadIdx.x;
    if (n >= B) return;
    const float4* u4 = (const float4*)(u_table + (size_t)user[n] * 32);
    const float4* y4 = (const float4*)(y2 + (size_t)n * 32);
    float acc = weff[64];
    #pragma unroll
    for (int q = 0; q < 8; ++q) {
        float4 a = u4[q];
        acc += a.x * weff[q * 4 + 0] + a.y * weff[q * 4 + 1]
             + a.z * weff[q * 4 + 2] + a.w * weff[q * 4 + 3];
    }
    #pragma unroll
    for (int q = 0; q < 8; ++q) {
        float4 a = y4[q];
        acc += a.x * weff[32 + q * 4 + 0] + a.y * weff[32 + q * 4 + 1]
             + a.z * weff[32 + q * 4 + 2] + a.w * weff[32 + q * 4 + 3];
    }
    out[n] = 1.f / (1.f + expf(-acc));
}

extern "C" void kernel_launch(void* const* d_in, const int* in_sizes, int n_in,
                              void* d_out, int out_size, void* d_ws, size_t ws_size,
                              hipStream_t stream)
{
    const int*   user    = (const int*)  d_in[0];
    const int*   item    = (const int*)  d_in[1];
    const int*   graph   = (const int*)  d_in[2];
    const float* u_table = (const float*)d_in[3];
    const float* i_table = (const float*)d_in[4];
    const float* W1      = (const float*)d_in[5];
    const float* a_src1  = (const float*)d_in[6];
    const float* a_dst1  = (const float*)d_in[7];
    const float* b1      = (const float*)d_in[8];
    const float* W2      = (const float*)d_in[9];
    const float* a_src2  = (const float*)d_in[10];
    const float* a_dst2  = (const float*)d_in[11];
    const float* b2      = (const float*)d_in[12];
    const float* lw1     = (const float*)d_in[13];
    const float* lb1     = (const float*)d_in[14];
    const float* lw2     = (const float*)d_in[15];
    const float* lb2     = (const float*)d_in[16];

    const int B  = in_sizes[0];
    const int N  = B;
    const int E  = in_sizes[2] / 2;
    const int Et = E + N;

    float* ws = (float*)d_ws;
    size_t off = 0;
    float* xh    = ws + off; off += (size_t)N * 192;
    float* asrc  = ws + off; off += (size_t)N * HP;
    float* adst  = ws + off; off += (size_t)N * HP;
    float* mbuf  = ws + off; off += (size_t)N * HP;
    float* denom = ws + off; off += (size_t)N * HP;
    float* eexp  = ws + off; off += (size_t)Et * NHEAD;
    float* y1    = ws + off; off += (size_t)N * 32;
    float* y2    = ws + off; off += (size_t)N * 32;
    float* weff  = ws + off; off += 72;

    const int egrid = (Et + 255) / 256;
    const int agrid = (Et * 32 + 255) / 256;
    const int igrid = (N * HP + 255) / 256;

    // ---- GAT layer 1 (input: i_table gathered by item) ----
    hipLaunchKernelGGL(k_node_prep, dim3(512), dim3(192), 0, stream,
        i_table, item, W1, a_src1, a_dst1, b1, xh, asrc, adst, mbuf, denom, y1, N);
    hipLaunchKernelGGL(k_edge_max, dim3(egrid), dim3(256), 0, stream,
        graph, E, N, asrc, adst, mbuf);
    hipLaunchKernelGGL(k_edge_exp, dim3(egrid), dim3(256), 0, stream,
        graph, E, N, asrc, adst, mbuf, eexp, denom);
    hipLaunchKernelGGL(k_inv, dim3(igrid), dim3(256), 0, stream, denom, N * HP);
    hipLaunchKernelGGL(k_edge_aggr, dim3(agrid), dim3(256), 0, stream,
        graph, E, N, eexp, denom, xh, y1);

    // ---- GAT layer 2 (input: y1) ----
    hipLaunchKernelGGL(k_node_prep, dim3(512), dim3(192), 0, stream,
        y1, (const int*)nullptr, W2, a_src2, a_dst2, b2, xh, asrc, adst, mbuf, denom, y2, N);
    hipLaunchKernelGGL(k_edge_max, dim3(egrid), dim3(256), 0, stream,
        graph, E, N, asrc, adst, mbuf);
    hipLaunchKernelGGL(k_edge_exp, dim3(egrid), dim3(256), 0, stream,
        graph, E, N, asrc, adst, mbuf, eexp, denom);
    hipLaunchKernelGGL(k_inv, dim3(igrid), dim3(256), 0, stream, denom, N * HP);
    hipLaunchKernelGGL(k_edge_aggr, dim3(agrid), dim3(256), 0, stream,
        graph, E, N, eexp, denom, xh, y2);

    // ---- MLP head (two affine layers collapsed; no activation between) ----
    hipLaunchKernelGGL(k_mlp_collapse, dim3(1), dim3(64), 0, stream,
        lw1, lb1, lw2, lb2, weff);
    hipLaunchKernelGGL(k_final, dim3((B + 255) / 256), dim3(256), 0, stream,
        user, u_table, y2, weff, (float*)d_out, B);
}

// Round 2
// 540.405 us; speedup vs baseline: 2.5266x; 2.5266x over previous
//
#include <hip/hip_runtime.h>
#include <math.h>

#define NHEAD 6
#define HP 8      // padded per-node head stride
#define NEG_SLOPE 0.2f

// ==================== CSR build (graph identical for both layers) ==========

__global__ __launch_bounds__(256) void k_init_deg(int* __restrict__ deg, int N)
{
    int i = blockIdx.x * blockDim.x + threadIdx.x;
    if (i < N) deg[i] = 1;                    // self-loop
}

__global__ __launch_bounds__(256) void k_count(const int* __restrict__ g, int E,
                                               int* __restrict__ deg)
{
    int e = blockIdx.x * blockDim.x + threadIdx.x;
    if (e < E) atomicAdd(&deg[g[E + e]], 1);
}

// Single-block exclusive scan over deg -> rowptr; also seeds cursor and the
// self-loop as the first entry of every node's adjacency segment.
__global__ __launch_bounds__(1024) void k_scan_csr(
    const int* __restrict__ deg, int* __restrict__ rowptr,
    int* __restrict__ cursor, int* __restrict__ adj, int N)
{
    __shared__ int wsum[16];
    const int t = threadIdx.x, lane = t & 63, w = t >> 6;
    int carry = 0;
    for (int base = 0; base < N; base += 1024) {
        int i = base + t;
        int v = (i < N) ? deg[i] : 0;
        int sv = v;
        #pragma unroll
        for (int off = 1; off < 64; off <<= 1) {
            int u = __shfl_up(sv, off);
            if (lane >= off) sv += u;
        }
        if (lane == 63) wsum[w] = sv;
        __syncthreads();
        if (w == 0) {
            int x = (lane < 16) ? wsum[lane] : 0;
            #pragma unroll
            for (int off = 1; off < 16; off <<= 1) {
                int u = __shfl_up(x, off);
                if (lane >= off) x += u;
            }
            if (lane < 16) wsum[lane] = x;    // inclusive scan of wave sums
        }
        __syncthreads();
        int woff = (w == 0) ? 0 : wsum[w - 1];
        int total = wsum[15];
        int excl = carry + woff + (sv - v);
        if (i < N) {
            rowptr[i] = excl;
            cursor[i] = excl + 1;             // edges go after the self-loop
            adj[excl] = i;                    // self-loop first
        }
        carry += total;
        __syncthreads();                      // wsum reused next tile
    }
}

__global__ __launch_bounds__(256) void k_scatter(const int* __restrict__ g, int E,
    int* __restrict__ cursor, int* __restrict__ adj)
{
    int e = blockIdx.x * blockDim.x + threadIdx.x;
    if (e >= E) return;
    int s = g[e], d = g[E + e];
    int pos = atomicAdd(&cursor[d], 1);
    adj[pos] = s;
}

// ==================== GAT layer kernels =====================================

// Per-node prep: xh = x @ W  ([N,32]@[32,192]); alpha_src/dst per head.
__global__ __launch_bounds__(192) void k_node_prep(
    const float* __restrict__ xsrc, const int* __restrict__ gidx,
    const float* __restrict__ W, const float* __restrict__ a_src,
    const float* __restrict__ a_dst,
    float* __restrict__ xh, float* __restrict__ asrc, float* __restrict__ adst,
    int N)
{
    __shared__ float Wl[32 * 192];
    __shared__ float xs[32];
    const int t = threadIdx.x;                // t = h*32 + c
    for (int i = t; i < 32 * 192; i += 192) Wl[i] = W[i];
    const float avs = a_src[t];
    const float avd = a_dst[t];
    const int h = t >> 5;
    const int c = t & 31;
    __syncthreads();

    for (int n = blockIdx.x; n < N; n += gridDim.x) {
        const int row = gidx ? gidx[n] : n;
        if (t < 32) xs[t] = xsrc[(size_t)row * 32 + t];
        __syncthreads();
        float acc = 0.f;
        #pragma unroll
        for (int k = 0; k < 32; ++k) acc = fmaf(xs[k], Wl[k * 192 + t], acc);
        xh[(size_t)n * 192 + t] = acc;
        float ps = acc * avs;
        float pd = acc * avd;
        #pragma unroll
        for (int off = 16; off > 0; off >>= 1) {
            ps += __shfl_xor(ps, off);
            pd += __shfl_xor(pd, off);
        }
        if (c == 0) { asrc[n * HP + h] = ps; adst[n * HP + h] = pd; }
        __syncthreads();
    }
}

// Fused per-destination softmax + aggregation. One 64-lane wave per node:
// lanes [0,32) handle heads {0,1,2} channel c, lanes [32,64) heads {3,4,5}.
// No max-subtraction (scores are O(0.1); softmax is shift-invariant).
__global__ __launch_bounds__(256) void k_gat_node(
    const int* __restrict__ rowptr, const int* __restrict__ deg,
    const int* __restrict__ adj,
    const float* __restrict__ asrc, const float* __restrict__ adst,
    const float* __restrict__ xh, const float* __restrict__ bias,
    float* __restrict__ y, int N)
{
    const int n = blockIdx.x * 4 + (threadIdx.x >> 6);
    if (n >= N) return;
    const int lane = threadIdx.x & 63;
    const int half = lane >> 5;
    const int c = lane & 31;
    const int hb = half * 3;                  // head base: 0 or 3

    const float ad0 = adst[n * HP + hb + 0];
    const float ad1 = adst[n * HP + hb + 1];
    const float ad2 = adst[n * HP + hb + 2];

    const int start = rowptr[n];
    const int end = start + deg[n];

    float acc0 = 0.f, acc1 = 0.f, acc2 = 0.f;
    float den0 = 0.f, den1 = 0.f, den2 = 0.f;

    int s_next = adj[start];
    for (int j = start; j < end; ++j) {
        const int s = s_next;
        if (j + 1 < end) s_next = adj[j + 1];
        const float* as = asrc + (size_t)s * HP + hb;
        float v0 = as[0] + ad0; v0 = (v0 >= 0.f) ? v0 : NEG_SLOPE * v0;
        float v1 = as[1] + ad1; v1 = (v1 >= 0.f) ? v1 : NEG_SLOPE * v1;
        float v2 = as[2] + ad2; v2 = (v2 >= 0.f) ? v2 : NEG_SLOPE * v2;
        float w0 = __expf(v0), w1 = __expf(v1), w2 = __expf(v2);
        den0 += w0; den1 += w1; den2 += w2;
        const float* xr = xh + (size_t)s * 192 + hb * 32 + c;
        acc0 = fmaf(w0, xr[0],  acc0);
        acc1 = fmaf(w1, xr[32], acc1);
        acc2 = fmaf(w2, xr[64], acc2);
    }
    float t = acc0 / (den0 + 1e-16f) + acc1 / (den1 + 1e-16f)
            + acc2 / (den2 + 1e-16f);
    t += __shfl_xor(t, 32);                   // combine the two head-halves
    if (half == 0) y[(size_t)n * 32 + c] = t * (1.f / 6.f) + bias[c];
}

// ==================== head ==================================================

__global__ void k_mlp_collapse(
    const float* __restrict__ lw1, const float* __restrict__ lb1,
    const float* __restrict__ lw2, const float* __restrict__ lb2,
    float* __restrict__ weff)
{
    int i = threadIdx.x;                      // 64 threads
    float acc = 0.f;
    for (int o = 0; o < 64; ++o) acc += lw1[i * 64 + o] * lw2[o];
    weff[i] = acc;
    if (i == 0) {
        float b = lb2[0];
        for (int o = 0; o < 64; ++o) b += lb1[o] * lw2[o];
        weff[64] = b;
    }
}

__global__ __launch_bounds__(256) void k_final(
    const int* __restrict__ user, const float* __restrict__ u_table,
    const float* __restrict__ y2, const float* __restrict__ weff,
    float* __restrict__ out, int B)
{
    int n = blockIdx.x * blockDim.x + threadIdx.x;
    if (n >= B) return;
    const float4* u4 = (const float4*)(u_table + (size_t)user[n] * 32);
    const float4* y4 = (const float4*)(y2 + (size_t)n * 32);
    float acc = weff[64];
    #pragma unroll
    for (int q = 0; q < 8; ++q) {
        float4 a = u4[q];
        acc += a.x * weff[q * 4 + 0] + a.y * weff[q * 4 + 1]
             + a.z * weff[q * 4 + 2] + a.w * weff[q * 4 + 3];
    }
    #pragma unroll
    for (int q = 0; q < 8; ++q) {
        float4 a = y4[q];
        acc += a.x * weff[32 + q * 4 + 0] + a.y * weff[32 + q * 4 + 1]
             + a.z * weff[32 + q * 4 + 2] + a.w * weff[32 + q * 4 + 3];
    }
    out[n] = 1.f / (1.f + expf(-acc));
}

// ==================== launch ================================================

extern "C" void kernel_launch(void* const* d_in, const int* in_sizes, int n_in,
                              void* d_out, int out_size, void* d_ws, size_t ws_size,
                              hipStream_t stream)
{
    const int*   user    = (const int*)  d_in[0];
    const int*   item    = (const int*)  d_in[1];
    const int*   graph   = (const int*)  d_in[2];
    const float* u_table = (const float*)d_in[3];
    const float* i_table = (const float*)d_in[4];
    const float* W1      = (const float*)d_in[5];
    const float* a_src1  = (const float*)d_in[6];
    const float* a_dst1  = (const float*)d_in[7];
    const float* b1      = (const float*)d_in[8];
    const float* W2      = (const float*)d_in[9];
    const float* a_src2  = (const float*)d_in[10];
    const float* a_dst2  = (const float*)d_in[11];
    const float* b2      = (const float*)d_in[12];
    const float* lw1     = (const float*)d_in[13];
    const float* lb1     = (const float*)d_in[14];
    const float* lw2     = (const float*)d_in[15];
    const float* lb2     = (const float*)d_in[16];

    const int B  = in_sizes[0];
    const int N  = B;
    const int E  = in_sizes[2] / 2;
    const int Et = E + N;

    float* ws = (float*)d_ws;
    size_t off = 0;
    float* xh     = ws + off; off += (size_t)N * 192;
    float* asrc   = ws + off; off += (size_t)N * HP;
    float* adst   = ws + off; off += (size_t)N * HP;
    float* y1     = ws + off; off += (size_t)N * 32;
    float* y2     = ws + off; off += (size_t)N * 32;
    float* weff   = ws + off; off += 128;
    int*   deg    = (int*)(ws + off); off += N;
    int*   rowptr = (int*)(ws + off); off += N;
    int*   cursor = (int*)(ws + off); off += N;
    int*   adj    = (int*)(ws + off); off += Et;

    const int egrid = (E + 255) / 256;
    const int ngrid = (N + 255) / 256;
    const int ggrid = (N + 3) / 4;

    // ---- CSR build (once; graph shared by both layers) ----
    hipLaunchKernelGGL(k_init_deg, dim3(ngrid), dim3(256), 0, stream, deg, N);
    hipLaunchKernelGGL(k_count,    dim3(egrid), dim3(256), 0, stream, graph, E, deg);
    hipLaunchKernelGGL(k_scan_csr, dim3(1), dim3(1024), 0, stream,
        deg, rowptr, cursor, adj, N);
    hipLaunchKernelGGL(k_scatter,  dim3(egrid), dim3(256), 0, stream,
        graph, E, cursor, adj);

    // ---- GAT layer 1 (input: i_table gathered by item) ----
    hipLaunchKernelGGL(k_node_prep, dim3(512), dim3(192), 0, stream,
        i_table, item, W1, a_src1, a_dst1, xh, asrc, adst, N);
    hipLaunchKernelGGL(k_gat_node, dim3(ggrid), dim3(256), 0, stream,
        rowptr, deg, adj, asrc, adst, xh, b1, y1, N);

    // ---- GAT layer 2 (input: y1) ----
    hipLaunchKernelGGL(k_node_prep, dim3(512), dim3(192), 0, stream,
        y1, (const int*)nullptr, W2, a_src2, a_dst2, xh, asrc, adst, N);
    hipLaunchKernelGGL(k_gat_node, dim3(ggrid), dim3(256), 0, stream,
        rowptr, deg, adj, asrc, adst, xh, b2, y2, N);

    // ---- MLP head (two affine layers collapsed; no activation between) ----
    hipLaunchKernelGGL(k_mlp_collapse, dim3(1), dim3(64), 0, stream,
        lw1, lb1, lw2, lb2, weff);
    hipLaunchKernelGGL(k_final, dim3((B + 255) / 256), dim3(256), 0, stream,
        user, u_table, y2, weff, (float*)d_out, B);
}

// Round 3
// 524.095 us; speedup vs baseline: 2.6052x; 1.0311x over previous
//
#include <hip/hip_runtime.h>
#include <math.h>

#define NHEAD 6
#define HP 8      // padded per-node head stride
#define NEG_SLOPE 0.2f
#define TILE 16   // nodes per k_node_prep block

// ==================== CSR build (graph identical for both layers) ==========

__global__ __launch_bounds__(256) void k_init_deg(int* __restrict__ deg, int N)
{
    int i = blockIdx.x * blockDim.x + threadIdx.x;
    if (i < N) deg[i] = 1;                    // self-loop
}

__global__ __launch_bounds__(256) void k_count(const int* __restrict__ g, int E,
                                               int* __restrict__ deg)
{
    int e = blockIdx.x * blockDim.x + threadIdx.x;
    if (e < E) atomicAdd(&deg[g[E + e]], 1);
}

// Two-level scan: per-1024-chunk sums, scan partials, then emit offsets.
__global__ __launch_bounds__(256) void k_block_sum(
    const int* __restrict__ deg, int* __restrict__ psum, int N)
{
    __shared__ int wsum[4];
    const int t = threadIdx.x, lane = t & 63, w = t >> 6;
    const int i0 = blockIdx.x * 1024 + t * 4;
    int s = 0;
    #pragma unroll
    for (int q = 0; q < 4; ++q) if (i0 + q < N) s += deg[i0 + q];
    #pragma unroll
    for (int off = 32; off > 0; off >>= 1) s += __shfl_xor(s, off);
    if (lane == 0) wsum[w] = s;
    __syncthreads();
    if (t == 0) psum[blockIdx.x] = wsum[0] + wsum[1] + wsum[2] + wsum[3];
}

__global__ void k_scan_partials(const int* __restrict__ psum,
                                int* __restrict__ poff, int NB)
{
    int lane = threadIdx.x;                   // 64 threads
    if (NB <= 64) {
        int v = (lane < NB) ? psum[lane] : 0;
        int incl = v;
        #pragma unroll
        for (int off = 1; off < 64; off <<= 1) {
            int u = __shfl_up(incl, off);
            if (lane >= off) incl += u;
        }
        if (lane < NB) poff[lane] = incl - v;
    } else if (lane == 0) {
        int run = 0;
        for (int b = 0; b < NB; ++b) { poff[b] = run; run += psum[b]; }
    }
}

__global__ __launch_bounds__(256) void k_emit(
    const int* __restrict__ deg, const int* __restrict__ poff,
    int* __restrict__ rowptr, int* __restrict__ cursor, int* __restrict__ adj,
    int N)
{
    __shared__ int wsum[4];
    const int t = threadIdx.x, lane = t & 63, w = t >> 6;
    const int i0 = blockIdx.x * 1024 + t * 4;
    int d[4];
    #pragma unroll
    for (int q = 0; q < 4; ++q) d[q] = (i0 + q < N) ? deg[i0 + q] : 0;
    int ts = d[0] + d[1] + d[2] + d[3];
    int incl = ts;
    #pragma unroll
    for (int off = 1; off < 64; off <<= 1) {
        int u = __shfl_up(incl, off);
        if (lane >= off) incl += u;
    }
    if (lane == 63) wsum[w] = incl;
    __syncthreads();
    int base = poff[blockIdx.x];
    for (int q = 0; q < w; ++q) base += wsum[q];
    int excl = base + (incl - ts);
    #pragma unroll
    for (int q = 0; q < 4; ++q) {
        int i = i0 + q;
        if (i < N) {
            rowptr[i] = excl;
            cursor[i] = excl + 1;             // edges go after the self-loop
            adj[excl] = i;                    // self-loop first
            excl += d[q];
        }
    }
}

__global__ __launch_bounds__(256) void k_scatter(const int* __restrict__ g, int E,
    int* __restrict__ cursor, int* __restrict__ adj)
{
    int e = blockIdx.x * blockDim.x + threadIdx.x;
    if (e >= E) return;
    int s = g[e], d = g[E + e];
    int pos = atomicAdd(&cursor[d], 1);
    adj[pos] = s;
}

// ==================== alpha weight folding ==================================
// asrc[n][h] = x[n,:] . (W a_src)[:,h]  -> fold a into W once per layer.
// wsd[k][j]: j<6 -> src head j, j>=6 -> dst head j-6.  Both layers in 1 block.
__global__ void k_alpha_weights(
    const float* __restrict__ W1, const float* __restrict__ as1,
    const float* __restrict__ ad1,
    const float* __restrict__ W2, const float* __restrict__ as2,
    const float* __restrict__ ad2,
    float* __restrict__ wsd1, float* __restrict__ wsd2)
{
    int t = threadIdx.x;                      // 768 threads
    int layer = t >> 9 ? 1 : (t >= 384);      // t/384
    int r = t - layer * 384;                  // r in [0,384)
    int k = r / 12, j = r - k * 12;
    const float* W = layer ? W2 : W1;
    const float* a = (j < 6) ? (layer ? as2 : as1) : (layer ? ad2 : ad1);
    int h = (j < 6) ? j : j - 6;
    float acc = 0.f;
    #pragma unroll
    for (int c = 0; c < 32; ++c)
        acc = fmaf(W[k * 192 + h * 32 + c], a[h * 32 + c], acc);
    (layer ? wsd2 : wsd1)[k * 12 + j] = acc;
}

// ==================== node prep =============================================
// One block per TILE nodes. Thread t owns output column t; W[:,t] in VGPRs.
__global__ __launch_bounds__(192) void k_node_prep(
    const float* __restrict__ xsrc, const int* __restrict__ gidx,
    const float* __restrict__ W, const float* __restrict__ wsd,
    float* __restrict__ xh, float* __restrict__ asrc, float* __restrict__ adst,
    int N)
{
    __shared__ float xs[TILE * 33];           // stride 33: bank-conflict-free
    __shared__ int   rows[TILE];
    __shared__ float wsd_s[32 * 12];
    const int t = threadIdx.x;

    float wcol[32];
    #pragma unroll
    for (int k = 0; k < 32; ++k) wcol[k] = W[k * 192 + t];
    for (int i = t; i < 32 * 12; i += 192) wsd_s[i] = wsd[i];

    const int n0 = blockIdx.x * TILE;
    if (t < TILE) {
        int n = n0 + t;
        rows[t] = (n < N) ? (gidx ? gidx[n] : n) : -1;
    }
    __syncthreads();
    if (t < TILE * 8) {                       // 16 rows x 8 float4
        int m = t >> 3, q = t & 7;
        int r = rows[m];
        float4 v = (r >= 0) ? *(const float4*)(xsrc + (size_t)r * 32 + q * 4)
                            : make_float4(0.f, 0.f, 0.f, 0.f);
        float* dst = xs + m * 33 + q * 4;
        dst[0] = v.x; dst[1] = v.y; dst[2] = v.z; dst[3] = v.w;
    }
    __syncthreads();

    const int nvalid = min(TILE, N - n0);
    float acc[TILE];
    #pragma unroll
    for (int m = 0; m < TILE; ++m) {
        float a = 0.f;
        const float* xr = xs + m * 33;
        #pragma unroll
        for (int k = 0; k < 32; ++k) a = fmaf(xr[k], wcol[k], a);
        acc[m] = a;
    }
    #pragma unroll
    for (int m = 0; m < TILE; ++m)
        if (m < nvalid) xh[(size_t)(n0 + m) * 192 + t] = acc[m];

    // alpha: thread t -> (node m = t/12, j = t%12); 16*12 = 192 = blockDim.
    {
        int m = t / 12, j = t - m * 12;
        if (m < nvalid) {
            const float* xr = xs + m * 33;
            float a = 0.f;
            #pragma unroll
            for (int k = 0; k < 32; ++k) a = fmaf(xr[k], wsd_s[k * 12 + j], a);
            if (j < 6) asrc[(size_t)(n0 + m) * HP + j] = a;
            else       adst[(size_t)(n0 + m) * HP + (j - 6)] = a;
        }
    }
}

// ==================== fused softmax + aggregation ===========================
// One 64-lane wave per node; lanes [0,32) heads {0,1,2}, [32,64) heads {3,4,5}.
// No max-subtraction (scores are O(0.1); softmax is shift-invariant).
__global__ __launch_bounds__(256) void k_gat_node(
    const int* __restrict__ rowptr, const int* __restrict__ deg,
    const int* __restrict__ adj,
    const float* __restrict__ asrc, const float* __restrict__ adst,
    const float* __restrict__ xh, const float* __restrict__ bias,
    float* __restrict__ y, int N)
{
    const int n = blockIdx.x * 4 + (threadIdx.x >> 6);
    if (n >= N) return;
    const int lane = threadIdx.x & 63;
    const int half = lane >> 5;
    const int c = lane & 31;
    const int hb = half * 3;                  // head base: 0 or 3

    const float ad0 = adst[(size_t)n * HP + hb + 0];
    const float ad1 = adst[(size_t)n * HP + hb + 1];
    const float ad2 = adst[(size_t)n * HP + hb + 2];

    const int start = rowptr[n];
    const int dg = deg[n];

    float acc0 = 0.f, acc1 = 0.f, acc2 = 0.f;
    float den0 = 0.f, den1 = 0.f, den2 = 0.f;

    for (int base = 0; base < dg; base += 64) {
        const int cnt = min(64, dg - base);
        const int adjv = (base + lane < dg) ? adj[start + base + lane] : 0;
        for (int j = 0; j < cnt; ++j) {
            const int s = __shfl(adjv, j);
            const float* as = asrc + (size_t)s * HP + hb;
            float v0 = as[0] + ad0; v0 = (v0 >= 0.f) ? v0 : NEG_SLOPE * v0;
            float v1 = as[1] + ad1; v1 = (v1 >= 0.f) ? v1 : NEG_SLOPE * v1;
            float v2 = as[2] + ad2; v2 = (v2 >= 0.f) ? v2 : NEG_SLOPE * v2;
            float w0 = __expf(v0), w1 = __expf(v1), w2 = __expf(v2);
            den0 += w0; den1 += w1; den2 += w2;
            const float* xr = xh + (size_t)s * 192 + hb * 32 + c;
            acc0 = fmaf(w0, xr[0],  acc0);
            acc1 = fmaf(w1, xr[32], acc1);
            acc2 = fmaf(w2, xr[64], acc2);
        }
    }
    float t = acc0 / (den0 + 1e-16f) + acc1 / (den1 + 1e-16f)
            + acc2 / (den2 + 1e-16f);
    t += __shfl_xor(t, 32);                   // combine the two head-halves
    if (half == 0) y[(size_t)n * 32 + c] = t * (1.f / 6.f) + bias[c];
}

// ==================== head ==================================================

__global__ void k_mlp_collapse(
    const float* __restrict__ lw1, const float* __restrict__ lb1,
    const float* __restrict__ lw2, const float* __restrict__ lb2,
    float* __restrict__ weff)
{
    int i = threadIdx.x;                      // 64 threads
    float acc = 0.f;
    for (int o = 0; o < 64; ++o) acc += lw1[i * 64 + o] * lw2[o];
    weff[i] = acc;
    if (i == 0) {
        float b = lb2[0];
        for (int o = 0; o < 64; ++o) b += lb1[o] * lw2[o];
        weff[64] = b;
    }
}

__global__ __launch_bounds__(256) void k_final(
    const int* __restrict__ user, const float* __restrict__ u_table,
    const float* __restrict__ y2, const float* __restrict__ weff,
    float* __restrict__ out, int B)
{
    int n = blockIdx.x * blockDim.x + threadIdx.x;
    if (n >= B) return;
    const float4* u4 = (const float4*)(u_table + (size_t)user[n] * 32);
    const float4* y4 = (const float4*)(y2 + (size_t)n * 32);
    float acc = weff[64];
    #pragma unroll
    for (int q = 0; q < 8; ++q) {
        float4 a = u4[q];
        acc += a.x * weff[q * 4 + 0] + a.y * weff[q * 4 + 1]
             + a.z * weff[q * 4 + 2] + a.w * weff[q * 4 + 3];
    }
    #pragma unroll
    for (int q = 0; q < 8; ++q) {
        float4 a = y4[q];
        acc += a.x * weff[32 + q * 4 + 0] + a.y * weff[32 + q * 4 + 1]
             + a.z * weff[32 + q * 4 + 2] + a.w * weff[32 + q * 4 + 3];
    }
    out[n] = 1.f / (1.f + expf(-acc));
}

// ==================== launch ================================================

extern "C" void kernel_launch(void* const* d_in, const int* in_sizes, int n_in,
                              void* d_out, int out_size, void* d_ws, size_t ws_size,
                              hipStream_t stream)
{
    const int*   user    = (const int*)  d_in[0];
    const int*   item    = (const int*)  d_in[1];
    const int*   graph   = (const int*)  d_in[2];
    const float* u_table = (const float*)d_in[3];
    const float* i_table = (const float*)d_in[4];
    const float* W1      = (const float*)d_in[5];
    const float* a_src1  = (const float*)d_in[6];
    const float* a_dst1  = (const float*)d_in[7];
    const float* b1      = (const float*)d_in[8];
    const float* W2      = (const float*)d_in[9];
    const float* a_src2  = (const float*)d_in[10];
    const float* a_dst2  = (const float*)d_in[11];
    const float* b2      = (const float*)d_in[12];
    const float* lw1     = (const float*)d_in[13];
    const float* lb1     = (const float*)d_in[14];
    const float* lw2     = (const float*)d_in[15];
    const float* lb2     = (const float*)d_in[16];

    const int B  = in_sizes[0];
    const int N  = B;
    const int E  = in_sizes[2] / 2;
    const int Et = E + N;
    const int NB = (N + 1023) / 1024;

    float* ws = (float*)d_ws;
    size_t off = 0;
    float* xh     = ws + off; off += (size_t)N * 192;
    float* asrc   = ws + off; off += (size_t)N * HP;
    float* adst   = ws + off; off += (size_t)N * HP;
    float* y1     = ws + off; off += (size_t)N * 32;
    float* y2     = ws + off; off += (size_t)N * 32;
    float* weff   = ws + off; off += 128;
    float* wsd1   = ws + off; off += 384;
    float* wsd2   = ws + off; off += 384;
    int*   deg    = (int*)(ws + off); off += N;
    int*   rowptr = (int*)(ws + off); off += N;
    int*   cursor = (int*)(ws + off); off += N;
    int*   psum   = (int*)(ws + off); off += NB + 1;
    int*   poff   = (int*)(ws + off); off += NB + 1;
    int*   adj    = (int*)(ws + off); off += Et;

    const int egrid = (E + 255) / 256;
    const int ngrid = (N + 255) / 256;
    const int ggrid = (N + 3) / 4;
    const int pgrid = (N + TILE - 1) / TILE;

    // ---- CSR build (once; graph shared by both layers) ----
    hipLaunchKernelGGL(k_init_deg, dim3(ngrid), dim3(256), 0, stream, deg, N);
    hipLaunchKernelGGL(k_count,    dim3(egrid), dim3(256), 0, stream, graph, E, deg);
    hipLaunchKernelGGL(k_block_sum, dim3(NB), dim3(256), 0, stream, deg, psum, N);
    hipLaunchKernelGGL(k_scan_partials, dim3(1), dim3(64), 0, stream, psum, poff, NB);
    hipLaunchKernelGGL(k_emit, dim3(NB), dim3(256), 0, stream,
        deg, poff, rowptr, cursor, adj, N);
    hipLaunchKernelGGL(k_scatter, dim3(egrid), dim3(256), 0, stream,
        graph, E, cursor, adj);

    // ---- fold alpha vectors into W (both layers) ----
    hipLaunchKernelGGL(k_alpha_weights, dim3(1), dim3(768), 0, stream,
        W1, a_src1, a_dst1, W2, a_src2, a_dst2, wsd1, wsd2);

    // ---- GAT layer 1 (input: i_table gathered by item) ----
    hipLaunchKernelGGL(k_node_prep, dim3(pgrid), dim3(192), 0, stream,
        i_table, item, W1, wsd1, xh, asrc, adst, N);
    hipLaunchKernelGGL(k_gat_node, dim3(ggrid), dim3(256), 0, stream,
        rowptr, deg, adj, asrc, adst, xh, b1, y1, N);

    // ---- GAT layer 2 (input: y1) ----
    hipLaunchKernelGGL(k_node_prep, dim3(pgrid), dim3(192), 0, stream,
        y1, (const int*)nullptr, W2, wsd2, xh, asrc, adst, N);
    hipLaunchKernelGGL(k_gat_node, dim3(ggrid), dim3(256), 0, stream,
        rowptr, deg, adj, asrc, adst, xh, b2, y2, N);

    // ---- MLP head (two affine layers collapsed; no activation between) ----
    hipLaunchKernelGGL(k_mlp_collapse, dim3(1), dim3(64), 0, stream,
        lw1, lb1, lw2, lb2, weff);
    hipLaunchKernelGGL(k_final, dim3((B + 255) / 256), dim3(256), 0, stream,
        user, u_table, y2, weff, (float*)d_out, B);
}

// Round 4
// 308.920 us; speedup vs baseline: 4.4199x; 1.6965x over previous
//
#include <hip/hip_runtime.h>
#include <hip/hip_fp16.h>
#include <math.h>

#define NHEAD 6
#define HP 8      // padded per-node head stride
#define NEG_SLOPE 0.2f
#define TILE 16   // nodes per k_node_prep block

// ==================== CSR build (graph identical for both layers) ==========

__global__ __launch_bounds__(256) void k_init_deg(int* __restrict__ deg, int N)
{
    int i = blockIdx.x * blockDim.x + threadIdx.x;
    if (i < N) deg[i] = 1;                    // self-loop
}

__global__ __launch_bounds__(256) void k_count(const int* __restrict__ g, int E,
                                               int* __restrict__ deg)
{
    int e = blockIdx.x * blockDim.x + threadIdx.x;
    if (e < E) atomicAdd(&deg[g[E + e]], 1);
}

// Two-level scan: per-1024-chunk sums, scan partials, then emit offsets.
__global__ __launch_bounds__(256) void k_block_sum(
    const int* __restrict__ deg, int* __restrict__ psum, int N)
{
    __shared__ int wsum[4];
    const int t = threadIdx.x, lane = t & 63, w = t >> 6;
    const int i0 = blockIdx.x * 1024 + t * 4;
    int s = 0;
    #pragma unroll
    for (int q = 0; q < 4; ++q) if (i0 + q < N) s += deg[i0 + q];
    #pragma unroll
    for (int off = 32; off > 0; off >>= 1) s += __shfl_xor(s, off);
    if (lane == 0) wsum[w] = s;
    __syncthreads();
    if (t == 0) psum[blockIdx.x] = wsum[0] + wsum[1] + wsum[2] + wsum[3];
}

__global__ void k_scan_partials(const int* __restrict__ psum,
                                int* __restrict__ poff, int NB)
{
    int lane = threadIdx.x;                   // 64 threads
    if (NB <= 64) {
        int v = (lane < NB) ? psum[lane] : 0;
        int incl = v;
        #pragma unroll
        for (int off = 1; off < 64; off <<= 1) {
            int u = __shfl_up(incl, off);
            if (lane >= off) incl += u;
        }
        if (lane < NB) poff[lane] = incl - v;
    } else if (lane == 0) {
        int run = 0;
        for (int b = 0; b < NB; ++b) { poff[b] = run; run += psum[b]; }
    }
}

__global__ __launch_bounds__(256) void k_emit(
    const int* __restrict__ deg, const int* __restrict__ poff,
    int* __restrict__ rowptr, int* __restrict__ cursor, int* __restrict__ adj,
    int N)
{
    __shared__ int wsum[4];
    const int t = threadIdx.x, lane = t & 63, w = t >> 6;
    const int i0 = blockIdx.x * 1024 + t * 4;
    int d[4];
    #pragma unroll
    for (int q = 0; q < 4; ++q) d[q] = (i0 + q < N) ? deg[i0 + q] : 0;
    int ts = d[0] + d[1] + d[2] + d[3];
    int incl = ts;
    #pragma unroll
    for (int off = 1; off < 64; off <<= 1) {
        int u = __shfl_up(incl, off);
        if (lane >= off) incl += u;
    }
    if (lane == 63) wsum[w] = incl;
    __syncthreads();
    int base = poff[blockIdx.x];
    for (int q = 0; q < w; ++q) base += wsum[q];
    int excl = base + (incl - ts);
    #pragma unroll
    for (int q = 0; q < 4; ++q) {
        int i = i0 + q;
        if (i < N) {
            rowptr[i] = excl;
            cursor[i] = excl + 1;             // edges go after the self-loop
            adj[excl] = i;                    // self-loop first
            excl += d[q];
        }
    }
}

__global__ __launch_bounds__(256) void k_scatter(const int* __restrict__ g, int E,
    int* __restrict__ cursor, int* __restrict__ adj)
{
    int e = blockIdx.x * blockDim.x + threadIdx.x;
    if (e >= E) return;
    int s = g[e], d = g[E + e];
    int pos = atomicAdd(&cursor[d], 1);
    adj[pos] = s;
}

// ==================== alpha weight folding ==================================
// asrc[n][h] = x[n,:] . (W a_src)[:,h]  -> fold a into W once per layer.
__global__ void k_alpha_weights(
    const float* __restrict__ W1, const float* __restrict__ as1,
    const float* __restrict__ ad1,
    const float* __restrict__ W2, const float* __restrict__ as2,
    const float* __restrict__ ad2,
    float* __restrict__ wsd1, float* __restrict__ wsd2)
{
    int t = threadIdx.x;                      // 768 threads
    int layer = (t >= 384);
    int r = t - layer * 384;                  // r in [0,384)
    int k = r / 12, j = r - k * 12;
    const float* W = layer ? W2 : W1;
    const float* a = (j < 6) ? (layer ? as2 : as1) : (layer ? ad2 : ad1);
    int h = (j < 6) ? j : j - 6;
    float acc = 0.f;
    #pragma unroll
    for (int c = 0; c < 32; ++c)
        acc = fmaf(W[k * 192 + h * 32 + c], a[h * 32 + c], acc);
    (layer ? wsd2 : wsd1)[k * 12 + j] = acc;
}

// ==================== node prep =============================================
// One block per TILE nodes. Thread t owns output column t; W[:,t] in VGPRs.
// Compute+store per node immediately (no acc[] array -> low VGPR).
__global__ __launch_bounds__(192) void k_node_prep(
    const float* __restrict__ xsrc, const int* __restrict__ gidx,
    const float* __restrict__ W, const float* __restrict__ wsd,
    __half* __restrict__ xh, float* __restrict__ asrc, float* __restrict__ adst,
    int N)
{
    __shared__ float xs[TILE * 33];           // stride 33: bank-conflict-free
    __shared__ int   rows[TILE];
    __shared__ float wsd_s[32 * 12];
    const int t = threadIdx.x;

    float wcol[32];
    #pragma unroll
    for (int k = 0; k < 32; ++k) wcol[k] = W[k * 192 + t];
    for (int i = t; i < 32 * 12; i += 192) wsd_s[i] = wsd[i];

    const int n0 = blockIdx.x * TILE;
    if (t < TILE) {
        int n = n0 + t;
        rows[t] = (n < N) ? (gidx ? gidx[n] : n) : -1;
    }
    __syncthreads();
    if (t < TILE * 8) {                       // 16 rows x 8 float4
        int m = t >> 3, q = t & 7;
        int r = rows[m];
        float4 v = (r >= 0) ? *(const float4*)(xsrc + (size_t)r * 32 + q * 4)
                            : make_float4(0.f, 0.f, 0.f, 0.f);
        float* dst = xs + m * 33 + q * 4;
        dst[0] = v.x; dst[1] = v.y; dst[2] = v.z; dst[3] = v.w;
    }
    __syncthreads();

    const int nvalid = min(TILE, N - n0);
    #pragma unroll 4
    for (int m = 0; m < TILE; ++m) {
        const float* xr = xs + m * 33;
        float a = 0.f;
        #pragma unroll
        for (int k = 0; k < 32; ++k) a = fmaf(xr[k], wcol[k], a);
        if (m < nvalid) xh[(size_t)(n0 + m) * 192 + t] = __float2half(a);
    }

    // alpha: thread t -> (node m = t/12, j = t%12); 16*12 = 192 = blockDim.
    {
        int m = t / 12, j = t - m * 12;
        if (m < nvalid) {
            const float* xr = xs + m * 33;
            float a = 0.f;
            #pragma unroll
            for (int k = 0; k < 32; ++k) a = fmaf(xr[k], wsd_s[k * 12 + j], a);
            if (j < 6) asrc[(size_t)(n0 + m) * HP + j] = a;
            else       adst[(size_t)(n0 + m) * HP + (j - 6)] = a;
        }
    }
}

// ==================== fused softmax + aggregation ===========================
// One 64-lane wave per node; lanes [0,32) heads {0,1,2}, [32,64) heads {3,4,5}.
// Per 32-edge chunk: lane el computes ITS half's 3 exp-weights for edge el in
// parallel; inner loop pulls them via bpermute from lane (lane&32)+j.
// No max-subtraction (scores are O(0.1); softmax is shift-invariant).
__global__ __launch_bounds__(256) void k_gat_node(
    const int* __restrict__ rowptr, const int* __restrict__ deg,
    const int* __restrict__ adj,
    const float* __restrict__ asrc, const float* __restrict__ adst,
    const __half* __restrict__ xh, const float* __restrict__ bias,
    float* __restrict__ y, int N)
{
    const int n = blockIdx.x * 4 + (threadIdx.x >> 6);
    if (n >= N) return;
    const int lane = threadIdx.x & 63;
    const int half = lane >> 5;
    const int c = lane & 31;
    const int hb = half * 3;                  // head base: 0 or 3
    const int el = lane & 31;                 // edge slot within chunk
    const int lb = lane & 32;                 // my half's source-lane base

    const float ad0 = adst[(size_t)n * HP + hb + 0];
    const float ad1 = adst[(size_t)n * HP + hb + 1];
    const float ad2 = adst[(size_t)n * HP + hb + 2];

    const int start = rowptr[n];
    const int dg = deg[n];

    float acc0 = 0.f, acc1 = 0.f, acc2 = 0.f;
    float den0 = 0.f, den1 = 0.f, den2 = 0.f;

    for (int base = 0; base < dg; base += 32) {
        const int cnt = min(32, dg - base);
        const int mye = base + el;
        const int s_l = (mye < dg) ? adj[start + mye] : 0;
        const float* as = asrc + (size_t)s_l * HP + hb;
        float v0 = as[0] + ad0; v0 = (v0 >= 0.f) ? v0 : NEG_SLOPE * v0;
        float v1 = as[1] + ad1; v1 = (v1 >= 0.f) ? v1 : NEG_SLOPE * v1;
        float v2 = as[2] + ad2; v2 = (v2 >= 0.f) ? v2 : NEG_SLOPE * v2;
        const float w0 = __expf(v0), w1 = __expf(v1), w2 = __expf(v2);
        for (int j = 0; j < cnt; ++j) {
            const int   s  = __shfl(s_l, lb + j);
            const float wa = __shfl(w0, lb + j);
            const float wb = __shfl(w1, lb + j);
            const float wc = __shfl(w2, lb + j);
            den0 += wa; den1 += wb; den2 += wc;
            const __half* xr = xh + (size_t)s * 192 + hb * 32 + c;
            acc0 = fmaf(wa, __half2float(xr[0]),  acc0);
            acc1 = fmaf(wb, __half2float(xr[32]), acc1);
            acc2 = fmaf(wc, __half2float(xr[64]), acc2);
        }
    }
    float tsum = acc0 / (den0 + 1e-16f) + acc1 / (den1 + 1e-16f)
               + acc2 / (den2 + 1e-16f);
    tsum += __shfl_xor(tsum, 32);             // combine the two head-halves
    if (half == 0) y[(size_t)n * 32 + c] = tsum * (1.f / 6.f) + bias[c];
}

// ==================== head ==================================================

__global__ void k_mlp_collapse(
    const float* __restrict__ lw1, const float* __restrict__ lb1,
    const float* __restrict__ lw2, const float* __restrict__ lb2,
    float* __restrict__ weff)
{
    int i = threadIdx.x;                      // 64 threads
    float acc = 0.f;
    for (int o = 0; o < 64; ++o) acc += lw1[i * 64 + o] * lw2[o];
    weff[i] = acc;
    if (i == 0) {
        float b = lb2[0];
        for (int o = 0; o < 64; ++o) b += lb1[o] * lw2[o];
        weff[64] = b;
    }
}

__global__ __launch_bounds__(256) void k_final(
    const int* __restrict__ user, const float* __restrict__ u_table,
    const float* __restrict__ y2, const float* __restrict__ weff,
    float* __restrict__ out, int B)
{
    int n = blockIdx.x * blockDim.x + threadIdx.x;
    if (n >= B) return;
    const float4* u4 = (const float4*)(u_table + (size_t)user[n] * 32);
    const float4* y4 = (const float4*)(y2 + (size_t)n * 32);
    float acc = weff[64];
    #pragma unroll
    for (int q = 0; q < 8; ++q) {
        float4 a = u4[q];
        acc += a.x * weff[q * 4 + 0] + a.y * weff[q * 4 + 1]
             + a.z * weff[q * 4 + 2] + a.w * weff[q * 4 + 3];
    }
    #pragma unroll
    for (int q = 0; q < 8; ++q) {
        float4 a = y4[q];
        acc += a.x * weff[32 + q * 4 + 0] + a.y * weff[32 + q * 4 + 1]
             + a.z * weff[32 + q * 4 + 2] + a.w * weff[32 + q * 4 + 3];
    }
    out[n] = 1.f / (1.f + expf(-acc));
}

// ==================== launch ================================================

extern "C" void kernel_launch(void* const* d_in, const int* in_sizes, int n_in,
                              void* d_out, int out_size, void* d_ws, size_t ws_size,
                              hipStream_t stream)
{
    const int*   user    = (const int*)  d_in[0];
    const int*   item    = (const int*)  d_in[1];
    const int*   graph   = (const int*)  d_in[2];
    const float* u_table = (const float*)d_in[3];
    const float* i_table = (const float*)d_in[4];
    const float* W1      = (const float*)d_in[5];
    const float* a_src1  = (const float*)d_in[6];
    const float* a_dst1  = (const float*)d_in[7];
    const float* b1      = (const float*)d_in[8];
    const float* W2      = (const float*)d_in[9];
    const float* a_src2  = (const float*)d_in[10];
    const float* a_dst2  = (const float*)d_in[11];
    const float* b2      = (const float*)d_in[12];
    const float* lw1     = (const float*)d_in[13];
    const float* lb1     = (const float*)d_in[14];
    const float* lw2     = (const float*)d_in[15];
    const float* lb2     = (const float*)d_in[16];

    const int B  = in_sizes[0];
    const int N  = B;
    const int E  = in_sizes[2] / 2;
    const int Et = E + N;
    const int NB = (N + 1023) / 1024;

    float* ws = (float*)d_ws;
    size_t off = 0;
    __half* xh    = (__half*)(ws + off); off += (size_t)N * 96;  // N*192 halves
    float* asrc   = ws + off; off += (size_t)N * HP;
    float* adst   = ws + off; off += (size_t)N * HP;
    float* y1     = ws + off; off += (size_t)N * 32;
    float* y2     = ws + off; off += (size_t)N * 32;
    float* weff   = ws + off; off += 128;
    float* wsd1   = ws + off; off += 384;
    float* wsd2   = ws + off; off += 384;
    int*   deg    = (int*)(ws + off); off += N;
    int*   rowptr = (int*)(ws + off); off += N;
    int*   cursor = (int*)(ws + off); off += N;
    int*   psum   = (int*)(ws + off); off += NB + 1;
    int*   poff   = (int*)(ws + off); off += NB + 1;
    int*   adj    = (int*)(ws + off); off += Et;

    const int egrid = (E + 255) / 256;
    const int ngrid = (N + 255) / 256;
    const int ggrid = (N + 3) / 4;
    const int pgrid = (N + TILE - 1) / TILE;

    // ---- CSR build (once; graph shared by both layers) ----
    hipLaunchKernelGGL(k_init_deg, dim3(ngrid), dim3(256), 0, stream, deg, N);
    hipLaunchKernelGGL(k_count,    dim3(egrid), dim3(256), 0, stream, graph, E, deg);
    hipLaunchKernelGGL(k_block_sum, dim3(NB), dim3(256), 0, stream, deg, psum, N);
    hipLaunchKernelGGL(k_scan_partials, dim3(1), dim3(64), 0, stream, psum, poff, NB);
    hipLaunchKernelGGL(k_emit, dim3(NB), dim3(256), 0, stream,
        deg, poff, rowptr, cursor, adj, N);
    hipLaunchKernelGGL(k_scatter, dim3(egrid), dim3(256), 0, stream,
        graph, E, cursor, adj);

    // ---- fold alpha vectors into W (both layers) ----
    hipLaunchKernelGGL(k_alpha_weights, dim3(1), dim3(768), 0, stream,
        W1, a_src1, a_dst1, W2, a_src2, a_dst2, wsd1, wsd2);

    // ---- GAT layer 1 (input: i_table gathered by item) ----
    hipLaunchKernelGGL(k_node_prep, dim3(pgrid), dim3(192), 0, stream,
        i_table, item, W1, wsd1, xh, asrc, adst, N);
    hipLaunchKernelGGL(k_gat_node, dim3(ggrid), dim3(256), 0, stream,
        rowptr, deg, adj, asrc, adst, xh, b1, y1, N);

    // ---- GAT layer 2 (input: y1) ----
    hipLaunchKernelGGL(k_node_prep, dim3(pgrid), dim3(192), 0, stream,
        y1, (const int*)nullptr, W2, wsd2, xh, asrc, adst, N);
    hipLaunchKernelGGL(k_gat_node, dim3(ggrid), dim3(256), 0, stream,
        rowptr, deg, adj, asrc, adst, xh, b2, y2, N);

    // ---- MLP head (two affine layers collapsed; no activation between) ----
    hipLaunchKernelGGL(k_mlp_collapse, dim3(1), dim3(64), 0, stream,
        lw1, lb1, lw2, lb2, weff);
    hipLaunchKernelGGL(k_final, dim3((B + 255) / 256), dim3(256), 0, stream,
        user, u_table, y2, weff, (float*)d_out, B);
}

// Round 5
// 300.775 us; speedup vs baseline: 4.5396x; 1.0271x over previous
//
#include <hip/hip_runtime.h>
#include <hip/hip_fp16.h>
#include <math.h>

#define NHEAD 6
#define HP 8      // padded per-node head stride
#define NEG_SLOPE 0.2f
#define TILE 16   // nodes per k_node_prep block

// ==================== CSR build (graph identical for both layers) ==========

__global__ __launch_bounds__(256) void k_init_deg(int* __restrict__ deg, int N)
{
    int i = blockIdx.x * blockDim.x + threadIdx.x;
    if (i < N) deg[i] = 1;                    // self-loop
}

__global__ __launch_bounds__(256) void k_count(const int* __restrict__ g, int E,
                                               int* __restrict__ deg)
{
    int e = blockIdx.x * blockDim.x + threadIdx.x;
    if (e < E) atomicAdd(&deg[g[E + e]], 1);
}

// Two-level scan: per-1024-chunk sums, scan partials, then emit offsets.
__global__ __launch_bounds__(256) void k_block_sum(
    const int* __restrict__ deg, int* __restrict__ psum, int N)
{
    __shared__ int wsum[4];
    const int t = threadIdx.x, lane = t & 63, w = t >> 6;
    const int i0 = blockIdx.x * 1024 + t * 4;
    int s = 0;
    #pragma unroll
    for (int q = 0; q < 4; ++q) if (i0 + q < N) s += deg[i0 + q];
    #pragma unroll
    for (int off = 32; off > 0; off >>= 1) s += __shfl_xor(s, off);
    if (lane == 0) wsum[w] = s;
    __syncthreads();
    if (t == 0) psum[blockIdx.x] = wsum[0] + wsum[1] + wsum[2] + wsum[3];
}

__global__ void k_scan_partials(const int* __restrict__ psum,
                                int* __restrict__ poff, int NB)
{
    int lane = threadIdx.x;                   // 64 threads
    if (NB <= 64) {
        int v = (lane < NB) ? psum[lane] : 0;
        int incl = v;
        #pragma unroll
        for (int off = 1; off < 64; off <<= 1) {
            int u = __shfl_up(incl, off);
            if (lane >= off) incl += u;
        }
        if (lane < NB) poff[lane] = incl - v;
    } else if (lane == 0) {
        int run = 0;
        for (int b = 0; b < NB; ++b) { poff[b] = run; run += psum[b]; }
    }
}

__global__ __launch_bounds__(256) void k_emit(
    const int* __restrict__ deg, const int* __restrict__ poff,
    int* __restrict__ rowptr, int* __restrict__ cursor, int* __restrict__ adj,
    int N)
{
    __shared__ int wsum[4];
    const int t = threadIdx.x, lane = t & 63, w = t >> 6;
    const int i0 = blockIdx.x * 1024 + t * 4;
    int d[4];
    #pragma unroll
    for (int q = 0; q < 4; ++q) d[q] = (i0 + q < N) ? deg[i0 + q] : 0;
    int ts = d[0] + d[1] + d[2] + d[3];
    int incl = ts;
    #pragma unroll
    for (int off = 1; off < 64; off <<= 1) {
        int u = __shfl_up(incl, off);
        if (lane >= off) incl += u;
    }
    if (lane == 63) wsum[w] = incl;
    __syncthreads();
    int base = poff[blockIdx.x];
    for (int q = 0; q < w; ++q) base += wsum[q];
    int excl = base + (incl - ts);
    #pragma unroll
    for (int q = 0; q < 4; ++q) {
        int i = i0 + q;
        if (i < N) {
            rowptr[i] = excl;
            cursor[i] = excl + 1;             // edges go after the self-loop
            adj[excl] = i;                    // self-loop first
            excl += d[q];
        }
    }
}

__global__ __launch_bounds__(256) void k_scatter(const int* __restrict__ g, int E,
    int* __restrict__ cursor, int* __restrict__ adj)
{
    int e = blockIdx.x * blockDim.x + threadIdx.x;
    if (e >= E) return;
    int s = g[e], d = g[E + e];
    int pos = atomicAdd(&cursor[d], 1);
    adj[pos] = s;
}

// ==================== alpha weight folding ==================================
// asrc[n][h] = x[n,:] . (W a_src)[:,h]  -> fold a into W once per layer.
__global__ void k_alpha_weights(
    const float* __restrict__ W1, const float* __restrict__ as1,
    const float* __restrict__ ad1,
    const float* __restrict__ W2, const float* __restrict__ as2,
    const float* __restrict__ ad2,
    float* __restrict__ wsd1, float* __restrict__ wsd2)
{
    int t = threadIdx.x;                      // 768 threads
    int layer = (t >= 384);
    int r = t - layer * 384;                  // r in [0,384)
    int k = r / 12, j = r - k * 12;
    const float* W = layer ? W2 : W1;
    const float* a = (j < 6) ? (layer ? as2 : as1) : (layer ? ad2 : ad1);
    int h = (j < 6) ? j : j - 6;
    float acc = 0.f;
    #pragma unroll
    for (int c = 0; c < 32; ++c)
        acc = fmaf(W[k * 192 + h * 32 + c], a[h * 32 + c], acc);
    (layer ? wsd2 : wsd1)[k * 12 + j] = acc;
}

// ==================== node prep =============================================
// One block per TILE nodes. Thread t owns output column t; W[:,t] in VGPRs.
// Compute+store per node immediately (no acc[] array -> low VGPR).
__global__ __launch_bounds__(192) void k_node_prep(
    const float* __restrict__ xsrc, const int* __restrict__ gidx,
    const float* __restrict__ W, const float* __restrict__ wsd,
    __half* __restrict__ xh, float* __restrict__ asrc, float* __restrict__ adst,
    int N)
{
    __shared__ float xs[TILE * 33];           // stride 33: bank-conflict-free
    __shared__ int   rows[TILE];
    __shared__ float wsd_s[32 * 12];
    const int t = threadIdx.x;

    float wcol[32];
    #pragma unroll
    for (int k = 0; k < 32; ++k) wcol[k] = W[k * 192 + t];
    for (int i = t; i < 32 * 12; i += 192) wsd_s[i] = wsd[i];

    const int n0 = blockIdx.x * TILE;
    if (t < TILE) {
        int n = n0 + t;
        rows[t] = (n < N) ? (gidx ? gidx[n] : n) : -1;
    }
    __syncthreads();
    if (t < TILE * 8) {                       // 16 rows x 8 float4
        int m = t >> 3, q = t & 7;
        int r = rows[m];
        float4 v = (r >= 0) ? *(const float4*)(xsrc + (size_t)r * 32 + q * 4)
                            : make_float4(0.f, 0.f, 0.f, 0.f);
        float* dst = xs + m * 33 + q * 4;
        dst[0] = v.x; dst[1] = v.y; dst[2] = v.z; dst[3] = v.w;
    }
    __syncthreads();

    const int nvalid = min(TILE, N - n0);
    #pragma unroll 4
    for (int m = 0; m < TILE; ++m) {
        const float* xr = xs + m * 33;
        float a = 0.f;
        #pragma unroll
        for (int k = 0; k < 32; ++k) a = fmaf(xr[k], wcol[k], a);
        if (m < nvalid) xh[(size_t)(n0 + m) * 192 + t] = __float2half(a);
    }

    // alpha: thread t -> (node m = t/12, j = t%12); 16*12 = 192 = blockDim.
    {
        int m = t / 12, j = t - m * 12;
        if (m < nvalid) {
            const float* xr = xs + m * 33;
            float a = 0.f;
            #pragma unroll
            for (int k = 0; k < 32; ++k) a = fmaf(xr[k], wsd_s[k * 12 + j], a);
            if (j < 6) asrc[(size_t)(n0 + m) * HP + j] = a;
            else       adst[(size_t)(n0 + m) * HP + (j - 6)] = a;
        }
    }
}

// ==================== fused softmax + aggregation ===========================
// One 64-lane wave per node; lanes [0,32) heads {0,1,2}, [32,64) heads {3,4,5}.
// Per 32-edge chunk: lane el computes ITS half's 3 exp-weights for edge el in
// parallel; inner loop pulls them via bpermute from lane (lane&32)+j.
// No max-subtraction (scores are O(0.1); softmax is shift-invariant).
__global__ __launch_bounds__(256) void k_gat_node(
    const int* __restrict__ rowptr, const int* __restrict__ deg,
    const int* __restrict__ adj,
    const float* __restrict__ asrc, const float* __restrict__ adst,
    const __half* __restrict__ xh, const float* __restrict__ bias,
    float* __restrict__ y, int N)
{
    const int n = blockIdx.x * 4 + (threadIdx.x >> 6);
    if (n >= N) return;
    const int lane = threadIdx.x & 63;
    const int half = lane >> 5;
    const int c = lane & 31;
    const int hb = half * 3;                  // head base: 0 or 3
    const int el = lane & 31;                 // edge slot within chunk
    const int lb = lane & 32;                 // my half's source-lane base

    const float ad0 = adst[(size_t)n * HP + hb + 0];
    const float ad1 = adst[(size_t)n * HP + hb + 1];
    const float ad2 = adst[(size_t)n * HP + hb + 2];

    const int start = rowptr[n];
    const int dg = deg[n];

    float acc0 = 0.f, acc1 = 0.f, acc2 = 0.f;
    float den0 = 0.f, den1 = 0.f, den2 = 0.f;

    for (int base = 0; base < dg; base += 32) {
        const int cnt = min(32, dg - base);
        const int mye = base + el;
        const int s_l = (mye < dg) ? adj[start + mye] : 0;
        const float* as = asrc + (size_t)s_l * HP + hb;
        float v0 = as[0] + ad0; v0 = (v0 >= 0.f) ? v0 : NEG_SLOPE * v0;
        float v1 = as[1] + ad1; v1 = (v1 >= 0.f) ? v1 : NEG_SLOPE * v1;
        float v2 = as[2] + ad2; v2 = (v2 >= 0.f) ? v2 : NEG_SLOPE * v2;
        const float w0 = __expf(v0), w1 = __expf(v1), w2 = __expf(v2);
        for (int j = 0; j < cnt; ++j) {
            const int   s  = __shfl(s_l, lb + j);
            const float wa = __shfl(w0, lb + j);
            const float wb = __shfl(w1, lb + j);
            const float wc = __shfl(w2, lb + j);
            den0 += wa; den1 += wb; den2 += wc;
            const __half* xr = xh + (size_t)s * 192 + hb * 32 + c;
            acc0 = fmaf(wa, __half2float(xr[0]),  acc0);
            acc1 = fmaf(wb, __half2float(xr[32]), acc1);
            acc2 = fmaf(wc, __half2float(xr[64]), acc2);
        }
    }
    float tsum = acc0 / (den0 + 1e-16f) + acc1 / (den1 + 1e-16f)
               + acc2 / (den2 + 1e-16f);
    tsum += __shfl_xor(tsum, 32);             // combine the two head-halves
    if (half == 0) y[(size_t)n * 32 + c] = tsum * (1.f / 6.f) + bias[c];
}

// ==================== head ==================================================

__global__ void k_mlp_collapse(
    const float* __restrict__ lw1, const float* __restrict__ lb1,
    const float* __restrict__ lw2, const float* __restrict__ lb2,
    float* __restrict__ weff)
{
    int i = threadIdx.x;                      // 64 threads
    float acc = 0.f;
    for (int o = 0; o < 64; ++o) acc += lw1[i * 64 + o] * lw2[o];
    weff[i] = acc;
    if (i == 0) {
        float b = lb2[0];
        for (int o = 0; o < 64; ++o) b += lb1[o] * lw2[o];
        weff[64] = b;
    }
}

__global__ __launch_bounds__(256) void k_final(
    const int* __restrict__ user, const float* __restrict__ u_table,
    const float* __restrict__ y2, const float* __restrict__ weff,
    float* __restrict__ out, int B)
{
    int n = blockIdx.x * blockDim.x + threadIdx.x;
    if (n >= B) return;
    const float4* u4 = (const float4*)(u_table + (size_t)user[n] * 32);
    const float4* y4 = (const float4*)(y2 + (size_t)n * 32);
    float acc = weff[64];
    #pragma unroll
    for (int q = 0; q < 8; ++q) {
        float4 a = u4[q];
        acc += a.x * weff[q * 4 + 0] + a.y * weff[q * 4 + 1]
             + a.z * weff[q * 4 + 2] + a.w * weff[q * 4 + 3];
    }
    #pragma unroll
    for (int q = 0; q < 8; ++q) {
        float4 a = y4[q];
        acc += a.x * weff[32 + q * 4 + 0] + a.y * weff[32 + q * 4 + 1]
             + a.z * weff[32 + q * 4 + 2] + a.w * weff[32 + q * 4 + 3];
    }
    out[n] = 1.f / (1.f + expf(-acc));
}

// ==================== launch ================================================

extern "C" void kernel_launch(void* const* d_in, const int* in_sizes, int n_in,
                              void* d_out, int out_size, void* d_ws, size_t ws_size,
                              hipStream_t stream)
{
    const int*   user    = (const int*)  d_in[0];
    const int*   item    = (const int*)  d_in[1];
    const int*   graph   = (const int*)  d_in[2];
    const float* u_table = (const float*)d_in[3];
    const float* i_table = (const float*)d_in[4];
    const float* W1      = (const float*)d_in[5];
    const float* a_src1  = (const float*)d_in[6];
    const float* a_dst1  = (const float*)d_in[7];
    const float* b1      = (const float*)d_in[8];
    const float* W2      = (const float*)d_in[9];
    const float* a_src2  = (const float*)d_in[10];
    const float* a_dst2  = (const float*)d_in[11];
    const float* b2      = (const float*)d_in[12];
    const float* lw1     = (const float*)d_in[13];
    const float* lb1     = (const float*)d_in[14];
    const float* lw2     = (const float*)d_in[15];
    const float* lb2     = (const float*)d_in[16];

    const int B  = in_sizes[0];
    const int N  = B;
    const int E  = in_sizes[2] / 2;
    const int Et = E + N;
    const int NB = (N + 1023) / 1024;

    float* ws = (float*)d_ws;
    size_t off = 0;
    __half* xh    = (__half*)(ws + off); off += (size_t)N * 96;  // N*192 halves
    float* asrc   = ws + off; off += (size_t)N * HP;
    float* adst   = ws + off; off += (size_t)N * HP;
    float* y1     = ws + off; off += (size_t)N * 32;
    float* y2     = ws + off; off += (size_t)N * 32;
    float* weff   = ws + off; off += 128;
    float* wsd1   = ws + off; off += 384;
    float* wsd2   = ws + off; off += 384;
    int*   deg    = (int*)(ws + off); off += N;
    int*   rowptr = (int*)(ws + off); off += N;
    int*   cursor = (int*)(ws + off); off += N;
    int*   psum   = (int*)(ws + off); off += NB + 1;
    int*   poff   = (int*)(ws + off); off += NB + 1;
    int*   adj    = (int*)(ws + off); off += Et;

    const int egrid = (E + 255) / 256;
    const int ngrid = (N + 255) / 256;
    const int ggrid = (N + 3) / 4;
    const int pgrid = (N + TILE - 1) / TILE;

    // ---- CSR build (once; graph shared by both layers) ----
    hipLaunchKernelGGL(k_init_deg, dim3(ngrid), dim3(256), 0, stream, deg, N);
    hipLaunchKernelGGL(k_count,    dim3(egrid), dim3(256), 0, stream, graph, E, deg);
    hipLaunchKernelGGL(k_block_sum, dim3(NB), dim3(256), 0, stream, deg, psum, N);
    hipLaunchKernelGGL(k_scan_partials, dim3(1), dim3(64), 0, stream, psum, poff, NB);
    hipLaunchKernelGGL(k_emit, dim3(NB), dim3(256), 0, stream,
        deg, poff, rowptr, cursor, adj, N);
    hipLaunchKernelGGL(k_scatter, dim3(egrid), dim3(256), 0, stream,
        graph, E, cursor, adj);

    // ---- fold alpha vectors into W (both layers) ----
    hipLaunchKernelGGL(k_alpha_weights, dim3(1), dim3(768), 0, stream,
        W1, a_src1, a_dst1, W2, a_src2, a_dst2, wsd1, wsd2);

    // ---- GAT layer 1 (input: i_table gathered by item) ----
    hipLaunchKernelGGL(k_node_prep, dim3(pgrid), dim3(192), 0, stream,
        i_table, item, W1, wsd1, xh, asrc, adst, N);
    hipLaunchKernelGGL(k_gat_node, dim3(ggrid), dim3(256), 0, stream,
        rowptr, deg, adj, asrc, adst, xh, b1, y1, N);

    // ---- GAT layer 2 (input: y1) ----
    hipLaunchKernelGGL(k_node_prep, dim3(pgrid), dim3(192), 0, stream,
        y1, (const int*)nullptr, W2, wsd2, xh, asrc, adst, N);
    hipLaunchKernelGGL(k_gat_node, dim3(ggrid), dim3(256), 0, stream,
        rowptr, deg, adj, asrc, adst, xh, b2, y2, N);

    // ---- MLP head (two affine layers collapsed; no activation between) ----
    hipLaunchKernelGGL(k_mlp_collapse, dim3(1), dim3(64), 0, stream,
        lw1, lb1, lw2, lb2, weff);
    hipLaunchKernelGGL(k_final, dim3((B + 255) / 256), dim3(256), 0, stream,
        user, u_table, y2, weff, (float*)d_out, B);
}

// Round 6
// 279.798 us; speedup vs baseline: 4.8799x; 1.0750x over previous
//
#include <hip/hip_runtime.h>
#include <hip/hip_fp16.h>
#include <math.h>

#define NHEAD 6
#define HP 8      // padded per-node head stride
#define NEG_SLOPE 0.2f
#define TILE 16   // nodes per k_node_prep block

// ==================== CSR build (graph identical for both layers) ==========

__global__ __launch_bounds__(256) void k_init_deg(int* __restrict__ deg, int N)
{
    int i = blockIdx.x * blockDim.x + threadIdx.x;
    if (i < N) deg[i] = 1;                    // self-loop
}

__global__ __launch_bounds__(256) void k_count(const int* __restrict__ g, int E,
                                               int* __restrict__ deg)
{
    int e = blockIdx.x * blockDim.x + threadIdx.x;
    if (e < E) atomicAdd(&deg[g[E + e]], 1);
}

// Two-level scan: per-1024-chunk sums, scan partials, then emit offsets.
__global__ __launch_bounds__(256) void k_block_sum(
    const int* __restrict__ deg, int* __restrict__ psum, int N)
{
    __shared__ int wsum[4];
    const int t = threadIdx.x, lane = t & 63, w = t >> 6;
    const int i0 = blockIdx.x * 1024 + t * 4;
    int s = 0;
    #pragma unroll
    for (int q = 0; q < 4; ++q) if (i0 + q < N) s += deg[i0 + q];
    #pragma unroll
    for (int off = 32; off > 0; off >>= 1) s += __shfl_xor(s, off);
    if (lane == 0) wsum[w] = s;
    __syncthreads();
    if (t == 0) psum[blockIdx.x] = wsum[0] + wsum[1] + wsum[2] + wsum[3];
}

__global__ void k_scan_partials(const int* __restrict__ psum,
                                int* __restrict__ poff, int NB)
{
    int lane = threadIdx.x;                   // 64 threads
    if (NB <= 64) {
        int v = (lane < NB) ? psum[lane] : 0;
        int incl = v;
        #pragma unroll
        for (int off = 1; off < 64; off <<= 1) {
            int u = __shfl_up(incl, off);
            if (lane >= off) incl += u;
        }
        if (lane < NB) poff[lane] = incl - v;
    } else if (lane == 0) {
        int run = 0;
        for (int b = 0; b < NB; ++b) { poff[b] = run; run += psum[b]; }
    }
}

__global__ __launch_bounds__(256) void k_emit(
    const int* __restrict__ deg, const int* __restrict__ poff,
    int* __restrict__ rowptr, int* __restrict__ cursor, int* __restrict__ adj,
    int N)
{
    __shared__ int wsum[4];
    const int t = threadIdx.x, lane = t & 63, w = t >> 6;
    const int i0 = blockIdx.x * 1024 + t * 4;
    int d[4];
    #pragma unroll
    for (int q = 0; q < 4; ++q) d[q] = (i0 + q < N) ? deg[i0 + q] : 0;
    int ts = d[0] + d[1] + d[2] + d[3];
    int incl = ts;
    #pragma unroll
    for (int off = 1; off < 64; off <<= 1) {
        int u = __shfl_up(incl, off);
        if (lane >= off) incl += u;
    }
    if (lane == 63) wsum[w] = incl;
    __syncthreads();
    int base = poff[blockIdx.x];
    for (int q = 0; q < w; ++q) base += wsum[q];
    int excl = base + (incl - ts);
    #pragma unroll
    for (int q = 0; q < 4; ++q) {
        int i = i0 + q;
        if (i < N) {
            rowptr[i] = excl;
            cursor[i] = excl + 1;             // edges go after the self-loop
            adj[excl] = i;                    // self-loop first
            excl += d[q];
        }
    }
}

__global__ __launch_bounds__(256) void k_scatter(const int* __restrict__ g, int E,
    int* __restrict__ cursor, int* __restrict__ adj)
{
    int e = blockIdx.x * blockDim.x + threadIdx.x;
    if (e >= E) return;
    int s = g[e], d = g[E + e];
    int pos = atomicAdd(&cursor[d], 1);
    adj[pos] = s;
}

// ==================== setup: alpha-weight folding + MLP collapse ============
// asrc[n][h] = x[n,:] . (W a_src)[:,h]  -> fold a into W once per layer.
// weff[i] = sum_o lw1[i][o]*lw2[o]; weff[64] = lb1.lw2 + lb2.
__global__ void k_setup(
    const float* __restrict__ W1, const float* __restrict__ as1,
    const float* __restrict__ ad1,
    const float* __restrict__ W2, const float* __restrict__ as2,
    const float* __restrict__ ad2,
    const float* __restrict__ lw1, const float* __restrict__ lb1,
    const float* __restrict__ lw2, const float* __restrict__ lb2,
    float* __restrict__ wsd1, float* __restrict__ wsd2,
    float* __restrict__ weff)
{
    int t = threadIdx.x;                      // 832 threads
    if (t < 768) {
        int layer = (t >= 384);
        int r = t - layer * 384;              // r in [0,384)
        int k = r / 12, j = r - k * 12;
        const float* W = layer ? W2 : W1;
        const float* a = (j < 6) ? (layer ? as2 : as1) : (layer ? ad2 : ad1);
        int h = (j < 6) ? j : j - 6;
        float acc = 0.f;
        #pragma unroll
        for (int c = 0; c < 32; ++c)
            acc = fmaf(W[k * 192 + h * 32 + c], a[h * 32 + c], acc);
        (layer ? wsd2 : wsd1)[k * 12 + j] = acc;
    } else {
        int i = t - 768;                      // 0..63
        float acc = 0.f;
        for (int o = 0; o < 64; ++o) acc += lw1[i * 64 + o] * lw2[o];
        weff[i] = acc;
        if (i == 0) {
            float b = lb2[0];
            for (int o = 0; o < 64; ++o) b += lb1[o] * lw2[o];
            weff[64] = b;
        }
    }
}

// ==================== node prep =============================================
// One block per TILE nodes. Thread t owns output column t; W[:,t] in VGPRs.
// Compute+store per node immediately (no acc[] array -> low VGPR).
__global__ __launch_bounds__(192) void k_node_prep(
    const float* __restrict__ xsrc, const int* __restrict__ gidx,
    const float* __restrict__ W, const float* __restrict__ wsd,
    __half* __restrict__ xh, float* __restrict__ asrc, float* __restrict__ adst,
    int N)
{
    __shared__ float xs[TILE * 33];           // stride 33: bank-conflict-free
    __shared__ int   rows[TILE];
    __shared__ float wsd_s[32 * 12];
    const int t = threadIdx.x;

    float wcol[32];
    #pragma unroll
    for (int k = 0; k < 32; ++k) wcol[k] = W[k * 192 + t];
    for (int i = t; i < 32 * 12; i += 192) wsd_s[i] = wsd[i];

    const int n0 = blockIdx.x * TILE;
    if (t < TILE) {
        int n = n0 + t;
        rows[t] = (n < N) ? (gidx ? gidx[n] : n) : -1;
    }
    __syncthreads();
    if (t < TILE * 8) {                       // 16 rows x 8 float4
        int m = t >> 3, q = t & 7;
        int r = rows[m];
        float4 v = (r >= 0) ? *(const float4*)(xsrc + (size_t)r * 32 + q * 4)
                            : make_float4(0.f, 0.f, 0.f, 0.f);
        float* dst = xs + m * 33 + q * 4;
        dst[0] = v.x; dst[1] = v.y; dst[2] = v.z; dst[3] = v.w;
    }
    __syncthreads();

    const int nvalid = min(TILE, N - n0);
    #pragma unroll 4
    for (int m = 0; m < TILE; ++m) {
        const float* xr = xs + m * 33;
        float a = 0.f;
        #pragma unroll
        for (int k = 0; k < 32; ++k) a = fmaf(xr[k], wcol[k], a);
        if (m < nvalid) xh[(size_t)(n0 + m) * 192 + t] = __float2half(a);
    }

    // alpha: thread t -> (node m = t/12, j = t%12); 16*12 = 192 = blockDim.
    {
        int m = t / 12, j = t - m * 12;
        if (m < nvalid) {
            const float* xr = xs + m * 33;
            float a = 0.f;
            #pragma unroll
            for (int k = 0; k < 32; ++k) a = fmaf(xr[k], wsd_s[k * 12 + j], a);
            if (j < 6) asrc[(size_t)(n0 + m) * HP + j] = a;
            else       adst[(size_t)(n0 + m) * HP + (j - 6)] = a;
        }
    }
}

// ==================== fused softmax + aggregation ===========================
// One 64-lane wave per node; lanes [0,32) heads {0,1,2}, [32,64) heads {3,4,5}.
// Weight phase: lane el computes its edge's 3 exp-weights (pad slots -> w=0)
// and accumulates its own denominators. Inner loop: trip count padded to a
// multiple of 4, explicit 4-wide bodies -> 4 independent bpermute+load chains.
// FUSE=1: layer 2 + MLP head + sigmoid fused (y never hits memory).
// No max-subtraction (scores are O(0.1); softmax is shift-invariant).
template<int FUSE>
__global__ __launch_bounds__(256) void k_gat_node(
    const int* __restrict__ rowptr, const int* __restrict__ deg,
    const int* __restrict__ adj,
    const float* __restrict__ asrc, const float* __restrict__ adst,
    const __half* __restrict__ xh, const float* __restrict__ bias,
    float* __restrict__ y, int N,
    const int* __restrict__ user, const float* __restrict__ u_table,
    const float* __restrict__ weff, float* __restrict__ out)
{
    const int n = blockIdx.x * 4 + (threadIdx.x >> 6);
    if (n >= N) return;
    const int lane = threadIdx.x & 63;
    const int half = lane >> 5;
    const int c = lane & 31;
    const int hb = half * 3;                  // head base: 0 or 3
    const int el = lane & 31;                 // edge slot within chunk
    const int lb = lane & 32;                 // my half's source-lane base

    const float ad0 = adst[(size_t)n * HP + hb + 0];
    const float ad1 = adst[(size_t)n * HP + hb + 1];
    const float ad2 = adst[(size_t)n * HP + hb + 2];

    const int start = rowptr[n];
    const int dg = deg[n];
    const char* xbase = (const char*)(xh + hb * 32 + c);

    float acc0 = 0.f, acc1 = 0.f, acc2 = 0.f;
    float dl0 = 0.f, dl1 = 0.f, dl2 = 0.f;    // per-lane partial denominators

    for (int base = 0; base < dg; base += 32) {
        const int rem = dg - base;
        const bool valid = el < rem;
        const int s_l = valid ? adj[start + base + el] : 0;
        const float* as = asrc + (size_t)s_l * HP + hb;
        float v0 = as[0] + ad0; v0 = (v0 >= 0.f) ? v0 : NEG_SLOPE * v0;
        float v1 = as[1] + ad1; v1 = (v1 >= 0.f) ? v1 : NEG_SLOPE * v1;
        float v2 = as[2] + ad2; v2 = (v2 >= 0.f) ? v2 : NEG_SLOPE * v2;
        const float w0 = valid ? __expf(v0) : 0.f;
        const float w1 = valid ? __expf(v1) : 0.f;
        const float w2 = valid ? __expf(v2) : 0.f;
        dl0 += w0; dl1 += w1; dl2 += w2;
        const int s_off = s_l * 384;          // byte offset of row

        const int cnt4 = min(32, (rem + 3) & ~3);
        for (int j = 0; j < cnt4; j += 4) {
            #pragma unroll
            for (int q = 0; q < 4; ++q) {
                const int   off = __shfl(s_off, lb + j + q);
                const float wa  = __shfl(w0,    lb + j + q);
                const float wb  = __shfl(w1,    lb + j + q);
                const float wc  = __shfl(w2,    lb + j + q);
                const __half* xr = (const __half*)(xbase + off);
                acc0 = fmaf(wa, __half2float(xr[0]),  acc0);
                acc1 = fmaf(wb, __half2float(xr[32]), acc1);
                acc2 = fmaf(wc, __half2float(xr[64]), acc2);
            }
        }
    }
    #pragma unroll
    for (int o = 16; o > 0; o >>= 1) {
        dl0 += __shfl_xor(dl0, o);
        dl1 += __shfl_xor(dl1, o);
        dl2 += __shfl_xor(dl2, o);
    }
    float tsum = acc0 / (dl0 + 1e-16f) + acc1 / (dl1 + 1e-16f)
               + acc2 / (dl2 + 1e-16f);
    tsum += __shfl_xor(tsum, 32);             // combine the two head-halves
    const float yv = tsum * (1.f / 6.f) + bias[c];
    if (FUSE == 0) {
        if (half == 0) y[(size_t)n * 32 + c] = yv;
    } else {
        // out[n] = sigmoid([u_emb | y].weff + b): half0 lanes dot the y part,
        // half1 lanes dot the u part, then full-wave reduce.
        float p = (half == 0) ? yv * weff[32 + c]
                              : u_table[(size_t)user[n] * 32 + c] * weff[c];
        #pragma unroll
        for (int o = 32; o > 0; o >>= 1) p += __shfl_xor(p, o);
        if (lane == 0) out[n] = 1.f / (1.f + __expf(-(p + weff[64])));
    }
}

// ==================== launch ================================================

extern "C" void kernel_launch(void* const* d_in, const int* in_sizes, int n_in,
                              void* d_out, int out_size, void* d_ws, size_t ws_size,
                              hipStream_t stream)
{
    const int*   user    = (const int*)  d_in[0];
    const int*   item    = (const int*)  d_in[1];
    const int*   graph   = (const int*)  d_in[2];
    const float* u_table = (const float*)d_in[3];
    const float* i_table = (const float*)d_in[4];
    const float* W1      = (const float*)d_in[5];
    const float* a_src1  = (const float*)d_in[6];
    const float* a_dst1  = (const float*)d_in[7];
    const float* b1      = (const float*)d_in[8];
    const float* W2      = (const float*)d_in[9];
    const float* a_src2  = (const float*)d_in[10];
    const float* a_dst2  = (const float*)d_in[11];
    const float* b2      = (const float*)d_in[12];
    const float* lw1     = (const float*)d_in[13];
    const float* lb1     = (const float*)d_in[14];
    const float* lw2     = (const float*)d_in[15];
    const float* lb2     = (const float*)d_in[16];

    const int B  = in_sizes[0];
    const int N  = B;
    const int E  = in_sizes[2] / 2;
    const int Et = E + N;
    const int NB = (N + 1023) / 1024;

    float* ws = (float*)d_ws;
    size_t off = 0;
    __half* xh    = (__half*)(ws + off); off += (size_t)N * 96;  // N*192 halves
    float* asrc   = ws + off; off += (size_t)N * HP;
    float* adst   = ws + off; off += (size_t)N * HP;
    float* y1     = ws + off; off += (size_t)N * 32;
    float* weff   = ws + off; off += 128;
    float* wsd1   = ws + off; off += 384;
    float* wsd2   = ws + off; off += 384;
    int*   deg    = (int*)(ws + off); off += N;
    int*   rowptr = (int*)(ws + off); off += N;
    int*   cursor = (int*)(ws + off); off += N;
    int*   psum   = (int*)(ws + off); off += NB + 1;
    int*   poff   = (int*)(ws + off); off += NB + 1;
    int*   adj    = (int*)(ws + off); off += Et;

    const int egrid = (E + 255) / 256;
    const int ngrid = (N + 255) / 256;
    const int ggrid = (N + 3) / 4;
    const int pgrid = (N + TILE - 1) / TILE;

    // ---- CSR build (once; graph shared by both layers) ----
    hipLaunchKernelGGL(k_init_deg, dim3(ngrid), dim3(256), 0, stream, deg, N);
    hipLaunchKernelGGL(k_count,    dim3(egrid), dim3(256), 0, stream, graph, E, deg);
    hipLaunchKernelGGL(k_block_sum, dim3(NB), dim3(256), 0, stream, deg, psum, N);
    hipLaunchKernelGGL(k_scan_partials, dim3(1), dim3(64), 0, stream, psum, poff, NB);
    hipLaunchKernelGGL(k_emit, dim3(NB), dim3(256), 0, stream,
        deg, poff, rowptr, cursor, adj, N);
    hipLaunchKernelGGL(k_scatter, dim3(egrid), dim3(256), 0, stream,
        graph, E, cursor, adj);

    // ---- setup: fold alpha vectors into W (both layers) + MLP collapse ----
    hipLaunchKernelGGL(k_setup, dim3(1), dim3(832), 0, stream,
        W1, a_src1, a_dst1, W2, a_src2, a_dst2,
        lw1, lb1, lw2, lb2, wsd1, wsd2, weff);

    // ---- GAT layer 1 (input: i_table gathered by item) ----
    hipLaunchKernelGGL(k_node_prep, dim3(pgrid), dim3(192), 0, stream,
        i_table, item, W1, wsd1, xh, asrc, adst, N);
    hipLaunchKernelGGL(k_gat_node<0>, dim3(ggrid), dim3(256), 0, stream,
        rowptr, deg, adj, asrc, adst, xh, b1, y1, N,
        (const int*)nullptr, (const float*)nullptr,
        (const float*)nullptr, (float*)nullptr);

    // ---- GAT layer 2 (input: y1) + fused MLP head + sigmoid ----
    hipLaunchKernelGGL(k_node_prep, dim3(pgrid), dim3(192), 0, stream,
        y1, (const int*)nullptr, W2, wsd2, xh, asrc, adst, N);
    hipLaunchKernelGGL(k_gat_node<1>, dim3(ggrid), dim3(256), 0, stream,
        rowptr, deg, adj, asrc, adst, xh, b2, (float*)nullptr, N,
        user, u_table, weff, (float*)d_out);
}

// Round 7
// 270.099 us; speedup vs baseline: 5.0551x; 1.0359x over previous
//
#include <hip/hip_runtime.h>
#include <hip/hip_fp16.h>
#include <math.h>

#define HP8 8     // halves per packed alpha row (6 heads + 2 pad)
#define NEG_SLOPE 0.2f
#define TILE 16   // nodes per k_node_prep block

// ==================== CSR build (graph identical for both layers) ==========

__global__ __launch_bounds__(256) void k_init_deg(int* __restrict__ deg, int N)
{
    int i = blockIdx.x * blockDim.x + threadIdx.x;
    if (i < N) deg[i] = 1;                    // self-loop
}

__global__ __launch_bounds__(256) void k_count(const int* __restrict__ g, int E,
                                               int* __restrict__ deg)
{
    int e = blockIdx.x * blockDim.x + threadIdx.x;
    if (e < E) atomicAdd(&deg[g[E + e]], 1);
}

// Two-level scan: per-1024-chunk sums, scan partials, then emit offsets.
__global__ __launch_bounds__(256) void k_block_sum(
    const int* __restrict__ deg, int* __restrict__ psum, int N)
{
    __shared__ int wsum[4];
    const int t = threadIdx.x, lane = t & 63, w = t >> 6;
    const int i0 = blockIdx.x * 1024 + t * 4;
    int s = 0;
    #pragma unroll
    for (int q = 0; q < 4; ++q) if (i0 + q < N) s += deg[i0 + q];
    #pragma unroll
    for (int off = 32; off > 0; off >>= 1) s += __shfl_xor(s, off);
    if (lane == 0) wsum[w] = s;
    __syncthreads();
    if (t == 0) psum[blockIdx.x] = wsum[0] + wsum[1] + wsum[2] + wsum[3];
}

__global__ void k_scan_partials(const int* __restrict__ psum,
                                int* __restrict__ poff, int NB)
{
    int lane = threadIdx.x;                   // 64 threads
    if (NB <= 64) {
        int v = (lane < NB) ? psum[lane] : 0;
        int incl = v;
        #pragma unroll
        for (int off = 1; off < 64; off <<= 1) {
            int u = __shfl_up(incl, off);
            if (lane >= off) incl += u;
        }
        if (lane < NB) poff[lane] = incl - v;
    } else if (lane == 0) {
        int run = 0;
        for (int b = 0; b < NB; ++b) { poff[b] = run; run += psum[b]; }
    }
}

__global__ __launch_bounds__(256) void k_emit(
    const int* __restrict__ deg, const int* __restrict__ poff,
    int* __restrict__ rowptr, int* __restrict__ cursor, int* __restrict__ adj,
    int N)
{
    __shared__ int wsum[4];
    const int t = threadIdx.x, lane = t & 63, w = t >> 6;
    const int i0 = blockIdx.x * 1024 + t * 4;
    int d[4];
    #pragma unroll
    for (int q = 0; q < 4; ++q) d[q] = (i0 + q < N) ? deg[i0 + q] : 0;
    int ts = d[0] + d[1] + d[2] + d[3];
    int incl = ts;
    #pragma unroll
    for (int off = 1; off < 64; off <<= 1) {
        int u = __shfl_up(incl, off);
        if (lane >= off) incl += u;
    }
    if (lane == 63) wsum[w] = incl;
    __syncthreads();
    int base = poff[blockIdx.x];
    for (int q = 0; q < w; ++q) base += wsum[q];
    int excl = base + (incl - ts);
    #pragma unroll
    for (int q = 0; q < 4; ++q) {
        int i = i0 + q;
        if (i < N) {
            rowptr[i] = excl;
            cursor[i] = excl + 1;             // edges go after the self-loop
            adj[excl] = i;                    // self-loop first
            excl += d[q];
        }
    }
}

__global__ __launch_bounds__(256) void k_scatter(const int* __restrict__ g, int E,
    int* __restrict__ cursor, int* __restrict__ adj)
{
    int e = blockIdx.x * blockDim.x + threadIdx.x;
    if (e >= E) return;
    int s = g[e], d = g[E + e];
    int pos = atomicAdd(&cursor[d], 1);
    adj[pos] = s;
}

// ==================== setup: alpha-weight folding + MLP collapse ============
__global__ void k_setup(
    const float* __restrict__ W1, const float* __restrict__ as1,
    const float* __restrict__ ad1,
    const float* __restrict__ W2, const float* __restrict__ as2,
    const float* __restrict__ ad2,
    const float* __restrict__ lw1, const float* __restrict__ lb1,
    const float* __restrict__ lw2, const float* __restrict__ lb2,
    float* __restrict__ wsd1, float* __restrict__ wsd2,
    float* __restrict__ weff)
{
    int t = threadIdx.x;                      // 832 threads
    if (t < 768) {
        int layer = (t >= 384);
        int r = t - layer * 384;              // r in [0,384)
        int k = r / 12, j = r - k * 12;
        const float* W = layer ? W2 : W1;
        const float* a = (j < 6) ? (layer ? as2 : as1) : (layer ? ad2 : ad1);
        int h = (j < 6) ? j : j - 6;
        float acc = 0.f;
        #pragma unroll
        for (int c = 0; c < 32; ++c)
            acc = fmaf(W[k * 192 + h * 32 + c], a[h * 32 + c], acc);
        (layer ? wsd2 : wsd1)[k * 12 + j] = acc;
    } else {
        int i = t - 768;                      // 0..63
        float acc = 0.f;
        for (int o = 0; o < 64; ++o) acc += lw1[i * 64 + o] * lw2[o];
        weff[i] = acc;
        if (i == 0) {
            float b = lb2[0];
            for (int o = 0; o < 64; ++o) b += lb1[o] * lw2[o];
            weff[64] = b;
        }
    }
}

// ==================== node prep =============================================
// One block per TILE nodes. Thread t owns output column t = h*32+c.
// xhp layout: [n][pair p=h>>1][c] as half2 dwords (row = 384 B).
// asrcp/adstp: [n][h] fp16, row stride HP8 halves (16 B).
__global__ __launch_bounds__(192) void k_node_prep(
    const float* __restrict__ xsrc, const int* __restrict__ gidx,
    const float* __restrict__ W, const float* __restrict__ wsd,
    __half* __restrict__ xhp, __half* __restrict__ asrcp,
    __half* __restrict__ adstp, int N)
{
    __shared__ float xs[TILE * 33];           // stride 33: bank-conflict-free
    __shared__ int   rows[TILE];
    __shared__ float wsd_s[32 * 12];
    const int t = threadIdx.x;

    float wcol[32];
    #pragma unroll
    for (int k = 0; k < 32; ++k) wcol[k] = W[k * 192 + t];
    for (int i = t; i < 32 * 12; i += 192) wsd_s[i] = wsd[i];

    const int h = t >> 5;
    const int c = t & 31;
    const int n0 = blockIdx.x * TILE;
    if (t < TILE) {
        int n = n0 + t;
        rows[t] = (n < N) ? (gidx ? gidx[n] : n) : -1;
    }
    __syncthreads();
    if (t < TILE * 8) {                       // 16 rows x 8 float4
        int m = t >> 3, q = t & 7;
        int r = rows[m];
        float4 v = (r >= 0) ? *(const float4*)(xsrc + (size_t)r * 32 + q * 4)
                            : make_float4(0.f, 0.f, 0.f, 0.f);
        float* dst = xs + m * 33 + q * 4;
        dst[0] = v.x; dst[1] = v.y; dst[2] = v.z; dst[3] = v.w;
    }
    __syncthreads();

    const int nvalid = min(TILE, N - n0);
    const int xoff = (h >> 1) * 64 + c * 2 + (h & 1);   // packed half index
    #pragma unroll 4
    for (int m = 0; m < TILE; ++m) {
        const float* xr = xs + m * 33;
        float a = 0.f;
        #pragma unroll
        for (int k = 0; k < 32; ++k) a = fmaf(xr[k], wcol[k], a);
        if (m < nvalid)
            xhp[(size_t)(n0 + m) * 192 + xoff] = __float2half(a);
    }

    // alpha: thread t -> (node m = t/12, j = t%12); 16*12 = 192 = blockDim.
    {
        int m = t / 12, j = t - m * 12;
        if (m < nvalid) {
            const float* xr = xs + m * 33;
            float a = 0.f;
            #pragma unroll
            for (int k = 0; k < 32; ++k) a = fmaf(xr[k], wsd_s[k * 12 + j], a);
            if (j < 6) asrcp[(size_t)(n0 + m) * HP8 + j] = __float2half(a);
            else       adstp[(size_t)(n0 + m) * HP8 + (j - 6)] = __float2half(a);
        }
    }
}

// ==================== fused softmax + aggregation ===========================
// One 64-lane wave per node. lane = channel c in both halves; the two halves
// process EVEN/ODD edges respectively (accumulators merged at the end).
// Per 32-edge chunk: lane el computes edge el's 6 exp-weights, packs a 16 B
// record (s_byteoff, w01, w23, w45 as half2) into LDS; gather loop reads the
// record with one broadcast ds_read_b128 and does 3 dword loads + 3 hfma2.
// No max-subtraction (scores are O(0.1); softmax is shift-invariant).
template<int FUSE>
__global__ __launch_bounds__(256) void k_gat_node(
    const int* __restrict__ rowptr, const int* __restrict__ deg,
    const int* __restrict__ adj,
    const __half* __restrict__ asrcp, const __half* __restrict__ adstp,
    const __half* __restrict__ xhp, const float* __restrict__ bias,
    float* __restrict__ y, int N,
    const int* __restrict__ user, const float* __restrict__ u_table,
    const float* __restrict__ weff, float* __restrict__ out)
{
    __shared__ float4 st[4][32];
    const int wv = threadIdx.x >> 6;
    const int n = blockIdx.x * 4 + wv;
    if (n >= N) return;
    const int lane = threadIdx.x & 63;
    const int half = lane >> 5;
    const int c = lane & 31;
    const int el = lane & 31;

    // dst alphas (uniform per node)
    const __half2 adA = *(const __half2*)(adstp + (size_t)n * HP8 + 0);
    const __half2 adB = *(const __half2*)(adstp + (size_t)n * HP8 + 2);
    const __half2 adC = *(const __half2*)(adstp + (size_t)n * HP8 + 4);
    const float ad0 = __low2float(adA), ad1 = __high2float(adA);
    const float ad2 = __low2float(adB), ad3 = __high2float(adB);
    const float ad4 = __low2float(adC), ad5 = __high2float(adC);

    const int start = rowptr[n];
    const int dg = deg[n];
    const char* xcb = (const char*)xhp + c * 4;

    __half2 acc0 = __float2half2_rn(0.f);
    __half2 acc1 = __float2half2_rn(0.f);
    __half2 acc2 = __float2half2_rn(0.f);
    float dl0 = 0.f, dl1 = 0.f, dl2 = 0.f, dl3 = 0.f, dl4 = 0.f, dl5 = 0.f;

    for (int base = 0; base < dg; base += 32) {
        const int rem = dg - base;
        const bool valid = el < rem;
        const int s = valid ? adj[start + base + el] : 0;
        // src alphas: one float4 = 8 halves (6 used)
        const float4 av = *(const float4*)(asrcp + (size_t)s * HP8);
        const __half2 aA = *(const __half2*)&av.x;
        const __half2 aB = *(const __half2*)&av.y;
        const __half2 aC = *(const __half2*)&av.z;
        float v0 = __low2float(aA) + ad0, v1 = __high2float(aA) + ad1;
        float v2 = __low2float(aB) + ad2, v3 = __high2float(aB) + ad3;
        float v4 = __low2float(aC) + ad4, v5 = __high2float(aC) + ad5;
        v0 = fmaxf(v0, NEG_SLOPE * v0); v1 = fmaxf(v1, NEG_SLOPE * v1);
        v2 = fmaxf(v2, NEG_SLOPE * v2); v3 = fmaxf(v3, NEG_SLOPE * v3);
        v4 = fmaxf(v4, NEG_SLOPE * v4); v5 = fmaxf(v5, NEG_SLOPE * v5);
        const float w0 = valid ? __expf(v0) : 0.f;
        const float w1 = valid ? __expf(v1) : 0.f;
        const float w2 = valid ? __expf(v2) : 0.f;
        const float w3 = valid ? __expf(v3) : 0.f;
        const float w4 = valid ? __expf(v4) : 0.f;
        const float w5 = valid ? __expf(v5) : 0.f;
        dl0 += w0; dl1 += w1; dl2 += w2; dl3 += w3; dl4 += w4; dl5 += w5;
        float4 rec;
        rec.x = __int_as_float(s * 384);
        const __half2 w01 = __floats2half2_rn(w0, w1);
        const __half2 w23 = __floats2half2_rn(w2, w3);
        const __half2 w45 = __floats2half2_rn(w4, w5);
        rec.y = *(const float*)&w01;
        rec.z = *(const float*)&w23;
        rec.w = *(const float*)&w45;
        if (lane < 32) st[wv][el] = rec;      // half 0 writes records

        // gather: halves take even/odd edges; pad records are zero-weight
        const int cnt = min(32, rem);
        int npairs = (cnt + 1) >> 1;
        npairs = (npairs + 1) & ~1;           // even trip, slots < 32 all valid
        for (int i = 0; i < npairs; i += 2) {
            #pragma unroll
            for (int q = 0; q < 2; ++q) {
                const float4 r = st[wv][2 * (i + q) + half];
                const char* p = xcb + __float_as_int(r.x);
                const uint d0 = *(const uint*)(p);
                const uint d1 = *(const uint*)(p + 128);
                const uint d2 = *(const uint*)(p + 256);
                acc0 = __hfma2(*(const __half2*)&r.y, *(const __half2*)&d0, acc0);
                acc1 = __hfma2(*(const __half2*)&r.z, *(const __half2*)&d1, acc1);
                acc2 = __hfma2(*(const __half2*)&r.w, *(const __half2*)&d2, acc2);
            }
        }
    }

    // combine halves (even/odd edge partial sums)
    float s0 = __low2float(acc0), s1 = __high2float(acc0);
    float s2 = __low2float(acc1), s3 = __high2float(acc1);
    float s4 = __low2float(acc2), s5 = __high2float(acc2);
    s0 += __shfl_xor(s0, 32); s1 += __shfl_xor(s1, 32);
    s2 += __shfl_xor(s2, 32); s3 += __shfl_xor(s3, 32);
    s4 += __shfl_xor(s4, 32); s5 += __shfl_xor(s5, 32);
    // reduce denominators over the 32 edge-slots (halves identical)
    #pragma unroll
    for (int o = 1; o <= 16; o <<= 1) {
        dl0 += __shfl_xor(dl0, o); dl1 += __shfl_xor(dl1, o);
        dl2 += __shfl_xor(dl2, o); dl3 += __shfl_xor(dl3, o);
        dl4 += __shfl_xor(dl4, o); dl5 += __shfl_xor(dl5, o);
    }
    const float r = s0 / (dl0 + 1e-16f) + s1 / (dl1 + 1e-16f)
                  + s2 / (dl2 + 1e-16f) + s3 / (dl3 + 1e-16f)
                  + s4 / (dl4 + 1e-16f) + s5 / (dl5 + 1e-16f);
    const float yv = r * (1.f / 6.f) + bias[c];

    if (FUSE == 0) {
        if (half == 0) y[(size_t)n * 32 + c] = yv;
    } else {
        // out[n] = sigmoid([u_emb | y].weff + b): half0 lanes dot the y part,
        // half1 lanes dot the u part, then full-wave reduce.
        float p = (half == 0) ? yv * weff[32 + c]
                              : u_table[(size_t)user[n] * 32 + c] * weff[c];
        #pragma unroll
        for (int o = 32; o > 0; o >>= 1) p += __shfl_xor(p, o);
        if (lane == 0) out[n] = 1.f / (1.f + __expf(-(p + weff[64])));
    }
}

// ==================== launch ================================================

extern "C" void kernel_launch(void* const* d_in, const int* in_sizes, int n_in,
                              void* d_out, int out_size, void* d_ws, size_t ws_size,
                              hipStream_t stream)
{
    const int*   user    = (const int*)  d_in[0];
    const int*   item    = (const int*)  d_in[1];
    const int*   graph   = (const int*)  d_in[2];
    const float* u_table = (const float*)d_in[3];
    const float* i_table = (const float*)d_in[4];
    const float* W1      = (const float*)d_in[5];
    const float* a_src1  = (const float*)d_in[6];
    const float* a_dst1  = (const float*)d_in[7];
    const float* b1      = (const float*)d_in[8];
    const float* W2      = (const float*)d_in[9];
    const float* a_src2  = (const float*)d_in[10];
    const float* a_dst2  = (const float*)d_in[11];
    const float* b2      = (const float*)d_in[12];
    const float* lw1     = (const float*)d_in[13];
    const float* lb1     = (const float*)d_in[14];
    const float* lw2     = (const float*)d_in[15];
    const float* lb2     = (const float*)d_in[16];

    const int B  = in_sizes[0];
    const int N  = B;
    const int E  = in_sizes[2] / 2;
    const int Et = E + N;
    const int NB = (N + 1023) / 1024;

    float* ws = (float*)d_ws;
    size_t off = 0;
    __half* xhp   = (__half*)(ws + off); off += (size_t)N * 96;  // N*192 halves
    __half* asrcp = (__half*)(ws + off); off += (size_t)N * 4;   // N*8 halves
    __half* adstp = (__half*)(ws + off); off += (size_t)N * 4;
    float* y1     = ws + off; off += (size_t)N * 32;
    float* weff   = ws + off; off += 128;
    float* wsd1   = ws + off; off += 384;
    float* wsd2   = ws + off; off += 384;
    int*   deg    = (int*)(ws + off); off += N;
    int*   rowptr = (int*)(ws + off); off += N;
    int*   cursor = (int*)(ws + off); off += N;
    int*   psum   = (int*)(ws + off); off += NB + 1;
    int*   poff   = (int*)(ws + off); off += NB + 1;
    int*   adj    = (int*)(ws + off); off += Et;

    const int egrid = (E + 255) / 256;
    const int ngrid = (N + 255) / 256;
    const int ggrid = (N + 3) / 4;
    const int pgrid = (N + TILE - 1) / TILE;

    // ---- CSR build (once; graph shared by both layers) ----
    hipLaunchKernelGGL(k_init_deg, dim3(ngrid), dim3(256), 0, stream, deg, N);
    hipLaunchKernelGGL(k_count,    dim3(egrid), dim3(256), 0, stream, graph, E, deg);
    hipLaunchKernelGGL(k_block_sum, dim3(NB), dim3(256), 0, stream, deg, psum, N);
    hipLaunchKernelGGL(k_scan_partials, dim3(1), dim3(64), 0, stream, psum, poff, NB);
    hipLaunchKernelGGL(k_emit, dim3(NB), dim3(256), 0, stream,
        deg, poff, rowptr, cursor, adj, N);
    hipLaunchKernelGGL(k_scatter, dim3(egrid), dim3(256), 0, stream,
        graph, E, cursor, adj);

    // ---- setup: fold alpha vectors into W (both layers) + MLP collapse ----
    hipLaunchKernelGGL(k_setup, dim3(1), dim3(832), 0, stream,
        W1, a_src1, a_dst1, W2, a_src2, a_dst2,
        lw1, lb1, lw2, lb2, wsd1, wsd2, weff);

    // ---- GAT layer 1 (input: i_table gathered by item) ----
    hipLaunchKernelGGL(k_node_prep, dim3(pgrid), dim3(192), 0, stream,
        i_table, item, W1, wsd1, xhp, asrcp, adstp, N);
    hipLaunchKernelGGL(k_gat_node<0>, dim3(ggrid), dim3(256), 0, stream,
        rowptr, deg, adj, asrcp, adstp, xhp, b1, y1, N,
        (const int*)nullptr, (const float*)nullptr,
        (const float*)nullptr, (float*)nullptr);

    // ---- GAT layer 2 (input: y1) + fused MLP head + sigmoid ----
    hipLaunchKernelGGL(k_node_prep, dim3(pgrid), dim3(192), 0, stream,
        y1, (const int*)nullptr, W2, wsd2, xhp, asrcp, adstp, N);
    hipLaunchKernelGGL(k_gat_node<1>, dim3(ggrid), dim3(256), 0, stream,
        rowptr, deg, adj, asrcp, adstp, xhp, b2, (float*)nullptr, N,
        user, u_table, weff, (float*)d_out);
}